// Round 11
// baseline (718.151 us; speedup 1.0000x reference)
//
#include <hip/hip_runtime.h>
#include <hip/hip_bf16.h>

#define SQ 2048
#define HH 2048
#define NHEAD 16
#define HD 128
#define QKVW (NHEAD*3*HD)   // 6144

typedef __attribute__((ext_vector_type(8))) short bf16x8;
typedef __attribute__((ext_vector_type(4))) float f32x4;
typedef __attribute__((ext_vector_type(16))) float f32x16;

__device__ inline unsigned short f2bf(float f) {
    union { float f; unsigned u; } x; x.f = f;
    unsigned r = x.u + 0x7FFFu + ((x.u >> 16) & 1u);
    return (unsigned short)(r >> 16);
}

__device__ inline unsigned pack_bf2(float a, float b) {
    return (unsigned)f2bf(a) | ((unsigned)f2bf(b) << 16);
}

__device__ inline float gelu_f(float x) {
    float x3 = x * (1.f + 0.044715f * x * x);
    return 0.5f * x * (1.f + tanhf(0.79788456f * x3));
}

// async global->LDS, 16B per lane. lds must be wave-uniform; g is per-lane.
__device__ inline void gld16(void* lds, const void* g) {
    __builtin_amdgcn_global_load_lds(
        (__attribute__((address_space(1))) void*)(g),
        (__attribute__((address_space(3))) void*)(lds), 16, 0, 0);
}

// ---------------- LayerNorm: fp32 in -> bf16 out ----------------
__global__ __launch_bounds__(256) void ln_kernel(
    const float* __restrict__ in, const float* __restrict__ g,
    const float* __restrict__ b, unsigned short* __restrict__ out)
{
    int row = blockIdx.x;
    int t = threadIdx.x, lane = t & 63, wid = t >> 6;
    const float4* rp = (const float4*)(in + (size_t)row * HH);
    float4 v0 = rp[t], v1 = rp[t + 256];
    float s  = v0.x + v0.y + v0.z + v0.w + v1.x + v1.y + v1.z + v1.w;
    float ss = v0.x*v0.x + v0.y*v0.y + v0.z*v0.z + v0.w*v0.w
             + v1.x*v1.x + v1.y*v1.y + v1.z*v1.z + v1.w*v1.w;
    #pragma unroll
    for (int o = 32; o; o >>= 1) { s += __shfl_down(s, o); ss += __shfl_down(ss, o); }
    __shared__ float r0[4], r1[4];
    if (lane == 0) { r0[wid] = s; r1[wid] = ss; }
    __syncthreads();
    s  = r0[0] + r0[1] + r0[2] + r0[3];
    ss = r1[0] + r1[1] + r1[2] + r1[3];
    float mu = s * (1.f / HH);
    float var = ss * (1.f / HH) - mu * mu;
    float rs = rsqrtf(var + 1e-5f);
    float4 g0 = ((const float4*)g)[t], g1 = ((const float4*)g)[t + 256];
    float4 b0 = ((const float4*)b)[t], b1 = ((const float4*)b)[t + 256];
    ushort4 o0, o1;
    o0.x = f2bf((v0.x - mu) * rs * g0.x + b0.x);
    o0.y = f2bf((v0.y - mu) * rs * g0.y + b0.y);
    o0.z = f2bf((v0.z - mu) * rs * g0.z + b0.z);
    o0.w = f2bf((v0.w - mu) * rs * g0.w + b0.w);
    o1.x = f2bf((v1.x - mu) * rs * g1.x + b1.x);
    o1.y = f2bf((v1.y - mu) * rs * g1.y + b1.y);
    o1.z = f2bf((v1.z - mu) * rs * g1.z + b1.z);
    o1.w = f2bf((v1.w - mu) * rs * g1.w + b1.w);
    ushort4* op = (ushort4*)(out + (size_t)row * HH);
    op[t] = o0; op[t + 256] = o1;
}

// ---------------- reduce: out = sum(4 partials) + res + bias ----------------
__global__ __launch_bounds__(256) void reduce4_kernel(
    const float* __restrict__ p0, const float* __restrict__ p1,
    const float* __restrict__ p2, const float* __restrict__ p3,
    const float* __restrict__ res, const float* __restrict__ bias,
    float* __restrict__ out, int n4, int nc4m1)
{
    int i = blockIdx.x * blockDim.x + threadIdx.x;
    int st = gridDim.x * blockDim.x;
    for (; i < n4; i += st) {
        float4 a = ((const float4*)p0)[i];
        float4 b = ((const float4*)p1)[i];
        float4 c = ((const float4*)p2)[i];
        float4 d = ((const float4*)p3)[i];
        float4 r = ((const float4*)res)[i];
        float4 bv = ((const float4*)bias)[i & nc4m1];
        float4 o;
        o.x = a.x + b.x + c.x + d.x + r.x + bv.x;
        o.y = a.y + b.y + c.y + d.y + r.y + bv.y;
        o.z = a.z + b.z + c.z + d.z + r.z + bv.z;
        o.w = a.w + b.w + c.w + d.w + r.w + bv.w;
        ((float4*)out)[i] = o;
    }
}

// ====== 128x128 GEMM, BK=32, 4 waves, 4 blocks/CU (m97-faithful TLP) ======
// C[M,N] = A[M,K]bf16 @ B[N,K]fp32^T (converted in-kernel). 256 thr = 4 waves
// (2M x 2N); per-wave C 64x64 (4x4 16x16 frags, 64 acc VGPR).
// LDS: Asm[2][128][32] (gld16, chunk-XOR s(r)=r&3), Bsm[2][128][40] (pad ->
// 80B stride spreads 16B writes over all 8 chunk-groups). 36 KiB -> 4
// blocks/CU = 4 INDEPENDENT barrier domains; a draining block's stall is
// covered by the other 3 (m114 TLP) — the m97 mechanism.
// Per K-tile: ds_write B(u+1) (regs, loads 1 iter old); gld16 A(u+1);
// load B(u+2) fp32 -> regs; 8 ds_read + 16 MFMA; __syncthreads().

// MODE: 0 = fp32 partial (no bias), 1 = bf16 + bias (+GELU), 2 = QKV splitV
template<int MODE, int GELU_ON>
__global__ __launch_bounds__(256, 4) void gemm128(
    const unsigned short* __restrict__ A, const float* __restrict__ B,
    const float* __restrict__ bias, void* __restrict__ outp,
    unsigned short* __restrict__ vtb, void* __restrict__ outp_hi,
    int N, int lda, int ldb, int kLen, int CH, int CW)
{
    __shared__ __align__(16) unsigned short Asm[2][128][32];   // 16 KiB
    __shared__ __align__(16) unsigned short Bsm[2][128][40];   // 20 KiB

    int t = threadIdx.x, lane = t & 63, wid = t >> 6;
    int lo = lane & 15, hi = lane >> 4;
    int wr = wid >> 1, wc = wid & 1;

    // 2D chunked XCD swizzle over (R = bz*gy+by, bx); CHxCW rectangle per XCD.
    int id = (blockIdx.z * gridDim.y + blockIdx.y) * gridDim.x + blockIdx.x;
    int xcd = id & 7, local = id >> 3;
    int cgx = gridDim.x / CW;
    int cr = xcd / cgx, cc = xcd - cr * cgx;
    int lr = local / CW, lc = local - lr * CW;
    int R  = cr * CH + lr;
    int bn = cc * CW + lc;
    int bm = R % gridDim.y;
    int bz = R / gridDim.y;
    int m0 = bm * 128, n0 = bn * 128;
    int kstart = bz * kLen;
    int nt = kLen >> 5;                     // BK = 32

    // A staging: 2 gld16/thread. call0 rows wid*16+(lane>>2), call1 +64.
    int rA = wid * 16 + (lane >> 2);
    const unsigned short* Abase = A + (size_t)m0 * lda + kstart;
    const unsigned short* Asrc0 = Abase + (size_t)rA * lda + (((lane & 3) ^ (rA & 3)) << 3);
    const unsigned short* Asrc1 = Asrc0 + (size_t)64 * lda;
    // B staging: thread t -> row t&127, half (t>>7): 16 fp32 -> 16 bf16.
    int rB = t & 127, hseg = t >> 7;
    const float* Bsrc = B + (size_t)(n0 + rB) * ldb + kstart + hseg * 16;

    // ---- prologue: A(0) in flight; Bs[0]<-B(0); p = B(1)
    gld16(&Asm[0][wid * 16][0], Asrc0);
    gld16(&Asm[0][64 + wid * 16][0], Asrc1);
    float4 q0 = *(const float4*)(Bsrc);
    float4 q1 = *(const float4*)(Bsrc + 4);
    float4 q2 = *(const float4*)(Bsrc + 8);
    float4 q3 = *(const float4*)(Bsrc + 12);
    {
        int4 w0, w1;
        w0.x = (int)pack_bf2(q0.x, q0.y); w0.y = (int)pack_bf2(q0.z, q0.w);
        w0.z = (int)pack_bf2(q1.x, q1.y); w0.w = (int)pack_bf2(q1.z, q1.w);
        w1.x = (int)pack_bf2(q2.x, q2.y); w1.y = (int)pack_bf2(q2.z, q2.w);
        w1.z = (int)pack_bf2(q3.x, q3.y); w1.w = (int)pack_bf2(q3.z, q3.w);
        *(int4*)&Bsm[0][rB][hseg * 16] = w0;
        *(int4*)&Bsm[0][rB][hseg * 16 + 8] = w1;
    }
    int k1 = (nt > 1) ? 32 : 0;
    float4 p0 = *(const float4*)(Bsrc + k1);
    float4 p1 = *(const float4*)(Bsrc + k1 + 4);
    float4 p2 = *(const float4*)(Bsrc + k1 + 8);
    float4 p3 = *(const float4*)(Bsrc + k1 + 12);
    __syncthreads();

    f32x4 acc[4][4] = {};
    for (int u = 0; u < nt; u++) {
        int buf = u & 1, nbuf = buf ^ 1;
        int t1 = (u + 1 < nt) ? u + 1 : nt - 1;
        int t2 = (u + 2 < nt) ? u + 2 : nt - 1;
        // write B(u+1) (p regs, drained by last barrier) -> Bsm[nbuf]
        {
            int4 w0, w1;
            w0.x = (int)pack_bf2(p0.x, p0.y); w0.y = (int)pack_bf2(p0.z, p0.w);
            w0.z = (int)pack_bf2(p1.x, p1.y); w0.w = (int)pack_bf2(p1.z, p1.w);
            w1.x = (int)pack_bf2(p2.x, p2.y); w1.y = (int)pack_bf2(p2.z, p2.w);
            w1.z = (int)pack_bf2(p3.x, p3.y); w1.w = (int)pack_bf2(p3.z, p3.w);
            *(int4*)&Bsm[nbuf][rB][hseg * 16] = w0;
            *(int4*)&Bsm[nbuf][rB][hseg * 16 + 8] = w1;
        }
        // stage A(u+1)
        gld16(&Asm[nbuf][wid * 16][0], Asrc0 + t1 * 32);
        gld16(&Asm[nbuf][64 + wid * 16][0], Asrc1 + t1 * 32);
        // load B(u+2) -> p
        p0 = *(const float4*)(Bsrc + t2 * 32);
        p1 = *(const float4*)(Bsrc + t2 * 32 + 4);
        p2 = *(const float4*)(Bsrc + t2 * 32 + 8);
        p3 = *(const float4*)(Bsrc + t2 * 32 + 12);
        // compute tile u
        __builtin_amdgcn_s_setprio(1);
        {
            const unsigned short (*LA)[32] = Asm[buf];
            const unsigned short (*LB)[40] = Bsm[buf];
            bf16x8 af[4], bfr[4];
            #pragma unroll
            for (int i = 0; i < 4; i++) {
                int r = wr * 64 + i * 16 + lo;
                af[i] = *(const bf16x8*)&LA[r][(hi ^ (lo & 3)) << 3];
            }
            #pragma unroll
            for (int c = 0; c < 4; c++)
                bfr[c] = *(const bf16x8*)&LB[wc * 64 + c * 16 + lo][hi * 8];
            #pragma unroll
            for (int i = 0; i < 4; i++)
                #pragma unroll
                for (int c = 0; c < 4; c++)
                    acc[i][c] = __builtin_amdgcn_mfma_f32_16x16x32_bf16(
                        bfr[c], af[i], acc[i][c], 0, 0, 0);
        }
        __builtin_amdgcn_s_setprio(0);
        __syncthreads();
    }

    // ---- epilogue ----  acc[i][c][j]: row M = m0+wr*64+i*16+lo,
    //                     col N = n0+wc*64+c*16+hi*4+j (j contiguous in N)
    if (MODE == 0) {
        float* po = ((bz < 2) ? (float*)outp : (float*)outp_hi)
                  + (size_t)(bz & 1) * SQ * (size_t)N;
        #pragma unroll
        for (int i = 0; i < 4; i++) {
            int gr = m0 + wr * 64 + i * 16 + lo;
            #pragma unroll
            for (int c = 0; c < 4; c++) {
                int gc = n0 + wc * 64 + c * 16 + hi * 4;
                *(f32x4*)&po[(size_t)gr * N + gc] = acc[i][c];
            }
        }
    } else if (MODE == 1) {
        unsigned short* op = (unsigned short*)outp;
        #pragma unroll
        for (int i = 0; i < 4; i++) {
            int gr = m0 + wr * 64 + i * 16 + lo;
            #pragma unroll
            for (int c = 0; c < 4; c++) {
                int gc = n0 + wc * 64 + c * 16 + hi * 4;
                float4 bi = *(const float4*)&bias[gc];
                float v0 = acc[i][c][0] + bi.x, v1 = acc[i][c][1] + bi.y;
                float v2 = acc[i][c][2] + bi.z, v3 = acc[i][c][3] + bi.w;
                if (GELU_ON) { v0 = gelu_f(v0); v1 = gelu_f(v1); v2 = gelu_f(v2); v3 = gelu_f(v3); }
                ushort4 o; o.x = f2bf(v0); o.y = f2bf(v1); o.z = f2bf(v2); o.w = f2bf(v3);
                *(ushort4*)&op[(size_t)gr * N + gc] = o;
            }
        }
    } else {
        // QKV: tile (128 cols) is entirely q, k, or v of head n0/384
        unsigned short* op = (unsigned short*)outp;
        int head = n0 / 384;
        int cat = (n0 >> 7) % 3;
        #pragma unroll
        for (int i = 0; i < 4; i++) {
            int gr = m0 + wr * 64 + i * 16 + lo;
            #pragma unroll
            for (int c = 0; c < 4; c++) {
                int gc = n0 + wc * 64 + c * 16 + hi * 4;
                float4 bi = *(const float4*)&bias[gc];
                float v0 = acc[i][c][0] + bi.x, v1 = acc[i][c][1] + bi.y;
                float v2 = acc[i][c][2] + bi.z, v3 = acc[i][c][3] + bi.w;
                if (cat == 2) {             // V columns -> transposed store
                    int d = wc * 64 + c * 16 + hi * 4;
                    unsigned short* vp = vtb + (size_t)(head * HD + d) * SQ + gr;
                    vp[0]      = f2bf(v0);
                    vp[SQ]     = f2bf(v1);
                    vp[2 * SQ] = f2bf(v2);
                    vp[3 * SQ] = f2bf(v3);
                } else {
                    ushort4 o; o.x = f2bf(v0); o.y = f2bf(v1); o.z = f2bf(v2); o.w = f2bf(v3);
                    *(ushort4*)&op[(size_t)gr * N + gc] = o;
                }
            }
        }
    }
}

// ---------------- Flash attention: 32x32 MFMA, causal + alibi ----------------
__global__ __launch_bounds__(128) void attn_kernel(
    const unsigned short* __restrict__ qkvB,  // [S][6144] bf16 (q,k valid)
    const unsigned short* __restrict__ vtb,   // [NH][HD][S] bf16
    unsigned short* __restrict__ ctx)         // [S][2048] bf16
{
    int w = blockIdx.x;
    int lid = (w & 7) * 64 + (w >> 3);
    int n = lid >> 5, qt = lid & 31;
    int t = threadIdx.x, lane = t & 63, wid = t >> 6;
    int l32 = lane & 31, h2 = lane >> 5;
    int q0 = qt * 64, qg = q0 + wid * 32 + l32;

    __shared__ __align__(16) unsigned short Ks[64][128];
    __shared__ __align__(16) unsigned short Vt[128][64];

    bf16x8 qf[8];
    const unsigned short* qp = qkvB + (size_t)qg * QKVW + n * 384 + h2 * 8;
    #pragma unroll
    for (int d8 = 0; d8 < 8; d8++)
        qf[d8] = *(const bf16x8*)(qp + d8 * 16);

    const float slope = exp2f(-0.5f * (float)(n + 1));
    const float inv = 0.08838834764831845f;   // 1/sqrt(128)
    float m = -INFINITY, lsum = 0.f;
    f32x16 ao[4] = {};

    int krow = lane >> 4, kch = lane & 15;
    int vrow = lane >> 3, vch = lane & 7;
    const unsigned short* kb_ = qkvB + n * 384 + 128;
    const unsigned short* vb_ = vtb + (size_t)n * HD * SQ;
    const char* ksb = (const char*)&Ks[0][0];
    const char* vsb = (const char*)&Vt[0][0];

    int nkb = qt + 1;
    for (int kb = 0; kb < nkb; kb++) {
        int k0 = kb * 64;
        __syncthreads();
        #pragma unroll
        for (int s = 0; s < 8; s++) {
            int r = wid * 32 + s * 4 + krow;
            gld16(&Ks[wid * 32 + s * 4][0],
                  kb_ + (size_t)(k0 + r) * QKVW + ((kch ^ (r & 7)) << 3));
            int dd = wid * 64 + s * 8 + vrow;
            gld16(&Vt[wid * 64 + s * 8][0],
                  vb_ + (size_t)dd * SQ + k0 + ((vch ^ (dd & 7)) << 3));
        }
        __syncthreads();

        f32x16 sc0 = {}, sc1 = {};
        #pragma unroll
        for (int d8 = 0; d8 < 8; d8++) {
            int ch = ((d8 * 2 + h2) ^ (l32 & 7)) << 4;
            bf16x8 kf0 = *(const bf16x8*)(ksb + l32 * 256 + ch);
            bf16x8 kf1 = *(const bf16x8*)(ksb + (32 + l32) * 256 + ch);
            sc0 = __builtin_amdgcn_mfma_f32_32x32x16_bf16(kf0, qf[d8], sc0, 0, 0, 0);
            sc1 = __builtin_amdgcn_mfma_f32_32x32x16_bf16(kf1, qf[d8], sc1, 0, 0, 0);
        }

        float tmax = -INFINITY;
        int last = (kb == nkb - 1);
        #pragma unroll
        for (int r = 0; r < 16; r++) {
            int kl = (r & 3) + 8 * (r >> 2) + 4 * h2;
            float s0 = sc0[r] * inv + slope * (float)(k0 + kl);
            float s1 = sc1[r] * inv + slope * (float)(k0 + 32 + kl);
            if (last) {
                if (k0 + kl > qg) s0 = -INFINITY;
                if (k0 + 32 + kl > qg) s1 = -INFINITY;
            }
            sc0[r] = s0; sc1[r] = s1;
            tmax = fmaxf(tmax, fmaxf(s0, s1));
        }
        tmax = fmaxf(tmax, __shfl_xor(tmax, 32));
        if (!__all(tmax <= m + 8.f)) {          // defer-max (T13)
            float mnew = fmaxf(m, tmax);
            float sca = __expf(m - mnew);
            m = mnew;
            lsum *= sca;
            #pragma unroll
            for (int db = 0; db < 4; db++)
                #pragma unroll
                for (int e = 0; e < 16; e++) ao[db][e] *= sca;
        }
        float psum = 0.f;
        #pragma unroll
        for (int r = 0; r < 16; r++) {
            sc0[r] = __expf(sc0[r] - m); psum += sc0[r];
            sc1[r] = __expf(sc1[r] - m); psum += sc1[r];
        }
        psum += __shfl_xor(psum, 32);
        lsum += psum;

        #pragma unroll
        for (int kstep = 0; kstep < 4; kstep++) {
            const int ks1 = kstep & 1;
            float a0, a1, a2, a3, b0, b1, b2, b3;
            if (kstep < 2) {
                a0 = sc0[8*ks1+0]; a1 = sc0[8*ks1+1]; a2 = sc0[8*ks1+2]; a3 = sc0[8*ks1+3];
                b0 = sc0[8*ks1+4]; b1 = sc0[8*ks1+5]; b2 = sc0[8*ks1+6]; b3 = sc0[8*ks1+7];
            } else {
                a0 = sc1[8*ks1+0]; a1 = sc1[8*ks1+1]; a2 = sc1[8*ks1+2]; a3 = sc1[8*ks1+3];
                b0 = sc1[8*ks1+4]; b1 = sc1[8*ks1+5]; b2 = sc1[8*ks1+6]; b3 = sc1[8*ks1+7];
            }
            unsigned ku0 = pack_bf2(h2 ? b0 : a0, h2 ? b1 : a1);
            unsigned ku1 = pack_bf2(h2 ? b2 : a2, h2 ? b3 : a3);
            unsigned su0 = pack_bf2(h2 ? a0 : b0, h2 ? a1 : b1);
            unsigned su1 = pack_bf2(h2 ? a2 : b2, h2 ? a3 : b3);
            unsigned r0 = (unsigned)__shfl_xor((int)su0, 32);
            unsigned r1 = (unsigned)__shfl_xor((int)su1, 32);
            union { int4 i; bf16x8 v; } u;
            u.i.x = h2 ? (int)r0  : (int)ku0;
            u.i.y = h2 ? (int)r1  : (int)ku1;
            u.i.z = h2 ? (int)ku0 : (int)r0;
            u.i.w = h2 ? (int)ku1 : (int)r1;
            bf16x8 pf = u.v;
            int ch = ((kstep * 2 + h2) ^ (l32 & 7)) << 4;
            #pragma unroll
            for (int db = 0; db < 4; db++) {
                bf16x8 vf = *(const bf16x8*)(vsb + (db * 32 + l32) * 128 + ch);
                ao[db] = __builtin_amdgcn_mfma_f32_32x32x16_bf16(vf, pf, ao[db], 0, 0, 0);
            }
        }
    }

    float rl = 1.f / lsum;
    #pragma unroll
    for (int db = 0; db < 4; db++)
        #pragma unroll
        for (int g = 0; g < 4; g++) {
            ushort4 o;
            o.x = f2bf(ao[db][g*4+0] * rl);
            o.y = f2bf(ao[db][g*4+1] * rl);
            o.z = f2bf(ao[db][g*4+2] * rl);
            o.w = f2bf(ao[db][g*4+3] * rl);
            *(ushort4*)(ctx + (size_t)qg * HH + n * HD + db * 32 + g * 8 + h2 * 4) = o;
        }
}

extern "C" void kernel_launch(void* const* d_in, const int* in_sizes, int n_in,
                              void* d_out, int out_size, void* d_ws, size_t ws_size,
                              hipStream_t stream) {
    const float* hs    = (const float*)d_in[0];
    const float* ln1g  = (const float*)d_in[4];
    const float* ln1b  = (const float*)d_in[5];
    const float* qkvw  = (const float*)d_in[6];
    const float* qkvb  = (const float*)d_in[7];
    const float* dw    = (const float*)d_in[8];
    const float* db    = (const float*)d_in[9];
    const float* ln2g  = (const float*)d_in[10];
    const float* ln2b  = (const float*)d_in[11];
    const float* f1w   = (const float*)d_in[12];
    const float* f1b   = (const float*)d_in[13];
    const float* f2w   = (const float*)d_in[14];
    const float* f2b   = (const float*)d_in[15];
    float* out = (float*)d_out;

    char* ws = (char*)d_ws;
    size_t off = 0;
    auto alloc = [&](size_t nbytes) {
        void* p = ws + off; off += (nbytes + 255) & ~(size_t)255; return p;
    };
    unsigned short* xbf  = (unsigned short*)alloc((size_t)SQ * HH * 2);        // [0, 8.4M)
    unsigned short* qkvB = (unsigned short*)alloc((size_t)SQ * QKVW * 2);      // [8.4M, 33.6M)
    unsigned short* vtB  = (unsigned short*)alloc((size_t)NHEAD * HD * SQ * 2);// [33.6M, 41.9M)
    unsigned short* ctx  = (unsigned short*)alloc((size_t)SQ * HH * 2);        // [41.9M, 50.3M)
    float*          attn = (float*)alloc((size_t)SQ * HH * 4);                 // [50.3M, 67.1M)
    unsigned short* y    = (unsigned short*)alloc((size_t)SQ * HH * 2);        // [67.1M, 75.5M)
    unsigned short* hdn  = (unsigned short*)alloc((size_t)SQ * 4 * HH * 2);    // [75.5M, 109.1M)
    float*          extra = (float*)alloc((size_t)2 * SQ * HH * 4);            // [109.1M, 142.6M)

    const size_t PQ = (size_t)SQ * HH;      // floats per partial (16.8 MB)
    float* part = (float*)ws;               // partials overlap dead early buffers

    ln_kernel<<<SQ, 256, 0, stream>>>(hs, ln1g, ln1b, xbf);

    // QKV: M=2048,N=6144,K=2048. grid 48x16 = 768 blocks; CH=8,CW=12.
    gemm128<2, 0><<<dim3(QKVW / 128, SQ / 128, 1), 256, 0, stream>>>(
        xbf, qkvw, qkvb, qkvB, vtB, nullptr, QKVW, HH, HH, HH, 8, 12);

    attn_kernel<<<512, 128, 0, stream>>>(qkvB, vtB, ctx);

    // dense: split-K x4 (16x16x4 = 1024 blocks, kLen=512); p0,p1 at ws, p2,p3 in dead hdn
    gemm128<0, 0><<<dim3(HH / 128, SQ / 128, 4), 256, 0, stream>>>(
        ctx, dw, nullptr, part, nullptr, hdn, HH, HH, HH, HH / 4, 8, 16);
    reduce4_kernel<<<2048, 256, 0, stream>>>(
        part, part + PQ, (float*)hdn, (float*)hdn + PQ, hs, db, attn, SQ * HH / 4, HH / 4 - 1);

    ln_kernel<<<SQ, 256, 0, stream>>>(attn, ln2g, ln2b, y);

    // FC1: M=2048,N=8192,K=2048. grid 64x16 = 1024 blocks; CH=8,CW=16.
    gemm128<1, 1><<<dim3(4 * HH / 128, SQ / 128, 1), 256, 0, stream>>>(
        y, f1w, f1b, hdn, nullptr, nullptr, 4 * HH, HH, HH, HH, 8, 16);

    // FC2: split-K x4 (16x16x4 = 1024 blocks, kLen=2048; 4*2048=8192=K);
    // p0,p1 at ws, p2,p3 at extra
    gemm128<0, 0><<<dim3(HH / 128, SQ / 128, 4), 256, 0, stream>>>(
        hdn, f2w, nullptr, part, nullptr, extra, HH, 4 * HH, 4 * HH, HH, 8, 16);
    reduce4_kernel<<<2048, 256, 0, stream>>>(
        part, part + PQ, extra, extra + PQ, attn, f2b, out, SQ * HH / 4, HH / 4 - 1);
}

// Round 12
// 691.032 us; speedup vs baseline: 1.0392x; 1.0392x over previous
//
#include <hip/hip_runtime.h>
#include <hip/hip_bf16.h>

#define SQ 2048
#define HH 2048
#define NHEAD 16
#define HD 128
#define QKVW (NHEAD*3*HD)   // 6144

typedef __attribute__((ext_vector_type(8))) short bf16x8;
typedef __attribute__((ext_vector_type(4))) float f32x4;
typedef __attribute__((ext_vector_type(16))) float f32x16;

__device__ inline unsigned short f2bf(float f) {
    union { float f; unsigned u; } x; x.f = f;
    unsigned r = x.u + 0x7FFFu + ((x.u >> 16) & 1u);
    return (unsigned short)(r >> 16);
}

__device__ inline unsigned pack_bf2(float a, float b) {
    return (unsigned)f2bf(a) | ((unsigned)f2bf(b) << 16);
}

__device__ inline float gelu_f(float x) {
    float x3 = x * (1.f + 0.044715f * x * x);
    return 0.5f * x * (1.f + tanhf(0.79788456f * x3));
}

// async global->LDS, 16B per lane. lds must be wave-uniform; g is per-lane.
__device__ inline void gld16(void* lds, const void* g) {
    __builtin_amdgcn_global_load_lds(
        (__attribute__((address_space(1))) void*)(g),
        (__attribute__((address_space(3))) void*)(lds), 16, 0, 0);
}

// ---------------- LayerNorm: fp32 in -> bf16 out ----------------
__global__ __launch_bounds__(256) void ln_kernel(
    const float* __restrict__ in, const float* __restrict__ g,
    const float* __restrict__ b, unsigned short* __restrict__ out)
{
    int row = blockIdx.x;
    int t = threadIdx.x, lane = t & 63, wid = t >> 6;
    const float4* rp = (const float4*)(in + (size_t)row * HH);
    float4 v0 = rp[t], v1 = rp[t + 256];
    float s  = v0.x + v0.y + v0.z + v0.w + v1.x + v1.y + v1.z + v1.w;
    float ss = v0.x*v0.x + v0.y*v0.y + v0.z*v0.z + v0.w*v0.w
             + v1.x*v1.x + v1.y*v1.y + v1.z*v1.z + v1.w*v1.w;
    #pragma unroll
    for (int o = 32; o; o >>= 1) { s += __shfl_down(s, o); ss += __shfl_down(ss, o); }
    __shared__ float r0[4], r1[4];
    if (lane == 0) { r0[wid] = s; r1[wid] = ss; }
    __syncthreads();
    s  = r0[0] + r0[1] + r0[2] + r0[3];
    ss = r1[0] + r1[1] + r1[2] + r1[3];
    float mu = s * (1.f / HH);
    float var = ss * (1.f / HH) - mu * mu;
    float rs = rsqrtf(var + 1e-5f);
    float4 g0 = ((const float4*)g)[t], g1 = ((const float4*)g)[t + 256];
    float4 b0 = ((const float4*)b)[t], b1 = ((const float4*)b)[t + 256];
    ushort4 o0, o1;
    o0.x = f2bf((v0.x - mu) * rs * g0.x + b0.x);
    o0.y = f2bf((v0.y - mu) * rs * g0.y + b0.y);
    o0.z = f2bf((v0.z - mu) * rs * g0.z + b0.z);
    o0.w = f2bf((v0.w - mu) * rs * g0.w + b0.w);
    o1.x = f2bf((v1.x - mu) * rs * g1.x + b1.x);
    o1.y = f2bf((v1.y - mu) * rs * g1.y + b1.y);
    o1.z = f2bf((v1.z - mu) * rs * g1.z + b1.z);
    o1.w = f2bf((v1.w - mu) * rs * g1.w + b1.w);
    ushort4* op = (ushort4*)(out + (size_t)row * HH);
    op[t] = o0; op[t + 256] = o1;
}

// ---------------- reduce: out = sum(4 partials) + res + bias ----------------
__global__ __launch_bounds__(256) void reduce4_kernel(
    const float* __restrict__ p0, const float* __restrict__ p1,
    const float* __restrict__ p2, const float* __restrict__ p3,
    const float* __restrict__ res, const float* __restrict__ bias,
    float* __restrict__ out, int n4, int nc4m1)
{
    int i = blockIdx.x * blockDim.x + threadIdx.x;
    int st = gridDim.x * blockDim.x;
    for (; i < n4; i += st) {
        float4 a = ((const float4*)p0)[i];
        float4 b = ((const float4*)p1)[i];
        float4 c = ((const float4*)p2)[i];
        float4 d = ((const float4*)p3)[i];
        float4 r = ((const float4*)res)[i];
        float4 bv = ((const float4*)bias)[i & nc4m1];
        float4 o;
        o.x = a.x + b.x + c.x + d.x + r.x + bv.x;
        o.y = a.y + b.y + c.y + d.y + r.y + bv.y;
        o.z = a.z + b.z + c.z + d.z + r.z + bv.z;
        o.w = a.w + b.w + c.w + d.w + r.w + bv.w;
        ((float4*)out)[i] = o;
    }
}

// ====== 128x128 GEMM, BK=64, single-buffer, 4 waves, 4 blocks/CU ======
// C[M,N] = A[M,K]bf16 @ B[N,K]fp32^T (converted in-kernel). 256 thr = 4 waves
// (2M x 2N); per-wave C 64x64 (4x4 frags, 2 K-halves -> 32 MFMA/tile).
// Amortization bet: per-K-iteration wall cost is ~constant (measured across
// 6 schedules) -> BK=64 halves iterations. LDS: Asm[128][64] (gld16, 8-chunk
// XOR swizzle, conflict-free frag reads), Bsm[128][72] (fp32 reg-staged,
// 144B rows: 2-way frag reads). 36.5 KB + 4 blocks/CU.
// Loop: {gld16 A(u); load B(u) fp32; pack; ds_write; sync; 32 MFMA; sync}.

// MODE: 0 = fp32 partial (no bias), 1 = bf16 + bias (+GELU), 2 = QKV splitV
template<int MODE, int GELU_ON>
__global__ __launch_bounds__(256, 4) void gemm128(
    const unsigned short* __restrict__ A, const float* __restrict__ B,
    const float* __restrict__ bias, void* __restrict__ outp,
    unsigned short* __restrict__ vtb, void* __restrict__ outp_hi,
    int N, int lda, int ldb, int kLen, int CH, int CW)
{
    __shared__ __align__(16) unsigned short Asm[128][64];   // 16 KiB
    __shared__ __align__(16) unsigned short Bsm[128][72];   // 18 KiB (144B rows)

    int t = threadIdx.x, lane = t & 63, wid = t >> 6;
    int lo = lane & 15, hi = lane >> 4;
    int wr = wid >> 1, wc = wid & 1;

    // 2D chunked XCD swizzle over (R = bz*gy+by, bx); CHxCW rectangle per XCD.
    int id = (blockIdx.z * gridDim.y + blockIdx.y) * gridDim.x + blockIdx.x;
    int xcd = id & 7, local = id >> 3;
    int cgx = gridDim.x / CW;
    int cr = xcd / cgx, cc = xcd - cr * cgx;
    int lr = local / CW, lc = local - lr * CW;
    int R  = cr * CH + lr;
    int bn = cc * CW + lc;
    int bm = R % gridDim.y;
    int bz = R / gridDim.y;
    int m0 = bm * 128, n0 = bn * 128;
    int kstart = bz * kLen;
    int nt = kLen >> 6;                     // BK = 64

    // A staging: 4 gld16/thread. call j: rows j*32 + (t>>3), chunk t&7.
    // Linear dest (16B x t within region); source pre-XOR'd chunk.
    int rAr = t >> 3;                       // 0..31 within region
    int cA  = (t & 7) ^ (rAr & 7);          // source chunk (involution)
    const unsigned short* AsrcBase = A + (size_t)m0 * lda + kstart + cA * 8;
    // B staging: row t&127, half t>>7 covers 32 fp32.
    int rB = t & 127, hB = t >> 7;
    const float* Bsrc = B + (size_t)(n0 + rB) * ldb + kstart + hB * 32;

    f32x4 acc[4][4] = {};
    for (int u = 0; u < nt; u++) {
        int ku = u * 64;
        // issue A -> LDS (async, drains at barrier)
        #pragma unroll
        for (int j = 0; j < 4; j++) {
            gld16(&Asm[j * 32 + wid * 8][0],
                  AsrcBase + (size_t)(j * 32 + rAr) * lda + ku);
        }
        // B fp32 -> regs -> pack -> LDS
        {
            const float* bp = Bsrc + ku;
            float4 f0 = *(const float4*)(bp);
            float4 f1 = *(const float4*)(bp + 4);
            float4 f2 = *(const float4*)(bp + 8);
            float4 f3 = *(const float4*)(bp + 12);
            float4 f4 = *(const float4*)(bp + 16);
            float4 f5 = *(const float4*)(bp + 20);
            float4 f6 = *(const float4*)(bp + 24);
            float4 f7 = *(const float4*)(bp + 28);
            int4 w0, w1, w2, w3;
            w0.x = (int)pack_bf2(f0.x, f0.y); w0.y = (int)pack_bf2(f0.z, f0.w);
            w0.z = (int)pack_bf2(f1.x, f1.y); w0.w = (int)pack_bf2(f1.z, f1.w);
            w1.x = (int)pack_bf2(f2.x, f2.y); w1.y = (int)pack_bf2(f2.z, f2.w);
            w1.z = (int)pack_bf2(f3.x, f3.y); w1.w = (int)pack_bf2(f3.z, f3.w);
            w2.x = (int)pack_bf2(f4.x, f4.y); w2.y = (int)pack_bf2(f4.z, f4.w);
            w2.z = (int)pack_bf2(f5.x, f5.y); w2.w = (int)pack_bf2(f5.z, f5.w);
            w3.x = (int)pack_bf2(f6.x, f6.y); w3.y = (int)pack_bf2(f6.z, f6.w);
            w3.z = (int)pack_bf2(f7.x, f7.y); w3.w = (int)pack_bf2(f7.z, f7.w);
            *(int4*)&Bsm[rB][hB * 32]      = w0;
            *(int4*)&Bsm[rB][hB * 32 + 8]  = w1;
            *(int4*)&Bsm[rB][hB * 32 + 16] = w2;
            *(int4*)&Bsm[rB][hB * 32 + 24] = w3;
        }
        __syncthreads();
        // compute: 2 K-halves x 4x4 frags
        __builtin_amdgcn_s_setprio(1);
        #pragma unroll
        for (int ks = 0; ks < 2; ks++) {
            int g = ks * 4 + hi;
            bf16x8 af[4], bfr[4];
            #pragma unroll
            for (int i = 0; i < 4; i++) {
                int r = wr * 64 + i * 16 + lo;
                af[i] = *(const bf16x8*)&Asm[r][(g ^ (lo & 7)) << 3];
            }
            #pragma unroll
            for (int c = 0; c < 4; c++)
                bfr[c] = *(const bf16x8*)&Bsm[wc * 64 + c * 16 + lo][g << 3];
            #pragma unroll
            for (int i = 0; i < 4; i++)
                #pragma unroll
                for (int c = 0; c < 4; c++)
                    acc[i][c] = __builtin_amdgcn_mfma_f32_16x16x32_bf16(
                        bfr[c], af[i], acc[i][c], 0, 0, 0);
        }
        __builtin_amdgcn_s_setprio(0);
        __syncthreads();
    }

    // ---- epilogue ----  acc[i][c][j]: row M = m0+wr*64+i*16+lo,
    //                     col N = n0+wc*64+c*16+hi*4+j (j contiguous in N)
    if (MODE == 0) {
        float* po = ((bz < 2) ? (float*)outp : (float*)outp_hi)
                  + (size_t)(bz & 1) * SQ * (size_t)N;
        #pragma unroll
        for (int i = 0; i < 4; i++) {
            int gr = m0 + wr * 64 + i * 16 + lo;
            #pragma unroll
            for (int c = 0; c < 4; c++) {
                int gc = n0 + wc * 64 + c * 16 + hi * 4;
                *(f32x4*)&po[(size_t)gr * N + gc] = acc[i][c];
            }
        }
    } else if (MODE == 1) {
        unsigned short* op = (unsigned short*)outp;
        #pragma unroll
        for (int i = 0; i < 4; i++) {
            int gr = m0 + wr * 64 + i * 16 + lo;
            #pragma unroll
            for (int c = 0; c < 4; c++) {
                int gc = n0 + wc * 64 + c * 16 + hi * 4;
                float4 bi = *(const float4*)&bias[gc];
                float v0 = acc[i][c][0] + bi.x, v1 = acc[i][c][1] + bi.y;
                float v2 = acc[i][c][2] + bi.z, v3 = acc[i][c][3] + bi.w;
                if (GELU_ON) { v0 = gelu_f(v0); v1 = gelu_f(v1); v2 = gelu_f(v2); v3 = gelu_f(v3); }
                ushort4 o; o.x = f2bf(v0); o.y = f2bf(v1); o.z = f2bf(v2); o.w = f2bf(v3);
                *(ushort4*)&op[(size_t)gr * N + gc] = o;
            }
        }
    } else {
        // QKV: tile (128 cols) is entirely q, k, or v of head n0/384
        unsigned short* op = (unsigned short*)outp;
        int head = n0 / 384;
        int cat = (n0 >> 7) % 3;
        #pragma unroll
        for (int i = 0; i < 4; i++) {
            int gr = m0 + wr * 64 + i * 16 + lo;
            #pragma unroll
            for (int c = 0; c < 4; c++) {
                int gc = n0 + wc * 64 + c * 16 + hi * 4;
                float4 bi = *(const float4*)&bias[gc];
                float v0 = acc[i][c][0] + bi.x, v1 = acc[i][c][1] + bi.y;
                float v2 = acc[i][c][2] + bi.z, v3 = acc[i][c][3] + bi.w;
                if (cat == 2) {             // V columns -> transposed store
                    int d = wc * 64 + c * 16 + hi * 4;
                    unsigned short* vp = vtb + (size_t)(head * HD + d) * SQ + gr;
                    vp[0]      = f2bf(v0);
                    vp[SQ]     = f2bf(v1);
                    vp[2 * SQ] = f2bf(v2);
                    vp[3 * SQ] = f2bf(v3);
                } else {
                    ushort4 o; o.x = f2bf(v0); o.y = f2bf(v1); o.z = f2bf(v2); o.w = f2bf(v3);
                    *(ushort4*)&op[(size_t)gr * N + gc] = o;
                }
            }
        }
    }
}

// ---------------- Flash attention: 32x32 MFMA, causal + alibi ----------------
__global__ __launch_bounds__(128) void attn_kernel(
    const unsigned short* __restrict__ qkvB,  // [S][6144] bf16 (q,k valid)
    const unsigned short* __restrict__ vtb,   // [NH][HD][S] bf16
    unsigned short* __restrict__ ctx)         // [S][2048] bf16
{
    int w = blockIdx.x;
    int lid = (w & 7) * 64 + (w >> 3);
    int n = lid >> 5, qt = lid & 31;
    int t = threadIdx.x, lane = t & 63, wid = t >> 6;
    int l32 = lane & 31, h2 = lane >> 5;
    int q0 = qt * 64, qg = q0 + wid * 32 + l32;

    __shared__ __align__(16) unsigned short Ks[64][128];
    __shared__ __align__(16) unsigned short Vt[128][64];

    bf16x8 qf[8];
    const unsigned short* qp = qkvB + (size_t)qg * QKVW + n * 384 + h2 * 8;
    #pragma unroll
    for (int d8 = 0; d8 < 8; d8++)
        qf[d8] = *(const bf16x8*)(qp + d8 * 16);

    const float slope = exp2f(-0.5f * (float)(n + 1));
    const float inv = 0.08838834764831845f;   // 1/sqrt(128)
    float m = -INFINITY, lsum = 0.f;
    f32x16 ao[4] = {};

    int krow = lane >> 4, kch = lane & 15;
    int vrow = lane >> 3, vch = lane & 7;
    const unsigned short* kb_ = qkvB + n * 384 + 128;
    const unsigned short* vb_ = vtb + (size_t)n * HD * SQ;
    const char* ksb = (const char*)&Ks[0][0];
    const char* vsb = (const char*)&Vt[0][0];

    int nkb = qt + 1;
    for (int kb = 0; kb < nkb; kb++) {
        int k0 = kb * 64;
        __syncthreads();
        #pragma unroll
        for (int s = 0; s < 8; s++) {
            int r = wid * 32 + s * 4 + krow;
            gld16(&Ks[wid * 32 + s * 4][0],
                  kb_ + (size_t)(k0 + r) * QKVW + ((kch ^ (r & 7)) << 3));
            int dd = wid * 64 + s * 8 + vrow;
            gld16(&Vt[wid * 64 + s * 8][0],
                  vb_ + (size_t)dd * SQ + k0 + ((vch ^ (dd & 7)) << 3));
        }
        __syncthreads();

        f32x16 sc0 = {}, sc1 = {};
        #pragma unroll
        for (int d8 = 0; d8 < 8; d8++) {
            int ch = ((d8 * 2 + h2) ^ (l32 & 7)) << 4;
            bf16x8 kf0 = *(const bf16x8*)(ksb + l32 * 256 + ch);
            bf16x8 kf1 = *(const bf16x8*)(ksb + (32 + l32) * 256 + ch);
            sc0 = __builtin_amdgcn_mfma_f32_32x32x16_bf16(kf0, qf[d8], sc0, 0, 0, 0);
            sc1 = __builtin_amdgcn_mfma_f32_32x32x16_bf16(kf1, qf[d8], sc1, 0, 0, 0);
        }

        float tmax = -INFINITY;
        int last = (kb == nkb - 1);
        #pragma unroll
        for (int r = 0; r < 16; r++) {
            int kl = (r & 3) + 8 * (r >> 2) + 4 * h2;
            float s0 = sc0[r] * inv + slope * (float)(k0 + kl);
            float s1 = sc1[r] * inv + slope * (float)(k0 + 32 + kl);
            if (last) {
                if (k0 + kl > qg) s0 = -INFINITY;
                if (k0 + 32 + kl > qg) s1 = -INFINITY;
            }
            sc0[r] = s0; sc1[r] = s1;
            tmax = fmaxf(tmax, fmaxf(s0, s1));
        }
        tmax = fmaxf(tmax, __shfl_xor(tmax, 32));
        if (!__all(tmax <= m + 8.f)) {          // defer-max (T13)
            float mnew = fmaxf(m, tmax);
            float sca = __expf(m - mnew);
            m = mnew;
            lsum *= sca;
            #pragma unroll
            for (int db = 0; db < 4; db++)
                #pragma unroll
                for (int e = 0; e < 16; e++) ao[db][e] *= sca;
        }
        float psum = 0.f;
        #pragma unroll
        for (int r = 0; r < 16; r++) {
            sc0[r] = __expf(sc0[r] - m); psum += sc0[r];
            sc1[r] = __expf(sc1[r] - m); psum += sc1[r];
        }
        psum += __shfl_xor(psum, 32);
        lsum += psum;

        #pragma unroll
        for (int kstep = 0; kstep < 4; kstep++) {
            const int ks1 = kstep & 1;
            float a0, a1, a2, a3, b0, b1, b2, b3;
            if (kstep < 2) {
                a0 = sc0[8*ks1+0]; a1 = sc0[8*ks1+1]; a2 = sc0[8*ks1+2]; a3 = sc0[8*ks1+3];
                b0 = sc0[8*ks1+4]; b1 = sc0[8*ks1+5]; b2 = sc0[8*ks1+6]; b3 = sc0[8*ks1+7];
            } else {
                a0 = sc1[8*ks1+0]; a1 = sc1[8*ks1+1]; a2 = sc1[8*ks1+2]; a3 = sc1[8*ks1+3];
                b0 = sc1[8*ks1+4]; b1 = sc1[8*ks1+5]; b2 = sc1[8*ks1+6]; b3 = sc1[8*ks1+7];
            }
            unsigned ku0 = pack_bf2(h2 ? b0 : a0, h2 ? b1 : a1);
            unsigned ku1 = pack_bf2(h2 ? b2 : a2, h2 ? b3 : a3);
            unsigned su0 = pack_bf2(h2 ? a0 : b0, h2 ? a1 : b1);
            unsigned su1 = pack_bf2(h2 ? a2 : b2, h2 ? a3 : b3);
            unsigned r0 = (unsigned)__shfl_xor((int)su0, 32);
            unsigned r1 = (unsigned)__shfl_xor((int)su1, 32);
            union { int4 i; bf16x8 v; } u;
            u.i.x = h2 ? (int)r0  : (int)ku0;
            u.i.y = h2 ? (int)r1  : (int)ku1;
            u.i.z = h2 ? (int)ku0 : (int)r0;
            u.i.w = h2 ? (int)ku1 : (int)r1;
            bf16x8 pf = u.v;
            int ch = ((kstep * 2 + h2) ^ (l32 & 7)) << 4;
            #pragma unroll
            for (int db = 0; db < 4; db++) {
                bf16x8 vf = *(const bf16x8*)(vsb + (db * 32 + l32) * 128 + ch);
                ao[db] = __builtin_amdgcn_mfma_f32_32x32x16_bf16(vf, pf, ao[db], 0, 0, 0);
            }
        }
    }

    float rl = 1.f / lsum;
    #pragma unroll
    for (int db = 0; db < 4; db++)
        #pragma unroll
        for (int g = 0; g < 4; g++) {
            ushort4 o;
            o.x = f2bf(ao[db][g*4+0] * rl);
            o.y = f2bf(ao[db][g*4+1] * rl);
            o.z = f2bf(ao[db][g*4+2] * rl);
            o.w = f2bf(ao[db][g*4+3] * rl);
            *(ushort4*)(ctx + (size_t)qg * HH + n * HD + db * 32 + g * 8 + h2 * 4) = o;
        }
}

extern "C" void kernel_launch(void* const* d_in, const int* in_sizes, int n_in,
                              void* d_out, int out_size, void* d_ws, size_t ws_size,
                              hipStream_t stream) {
    const float* hs    = (const float*)d_in[0];
    const float* ln1g  = (const float*)d_in[4];
    const float* ln1b  = (const float*)d_in[5];
    const float* qkvw  = (const float*)d_in[6];
    const float* qkvb  = (const float*)d_in[7];
    const float* dw    = (const float*)d_in[8];
    const float* db    = (const float*)d_in[9];
    const float* ln2g  = (const float*)d_in[10];
    const float* ln2b  = (const float*)d_in[11];
    const float* f1w   = (const float*)d_in[12];
    const float* f1b   = (const float*)d_in[13];
    const float* f2w   = (const float*)d_in[14];
    const float* f2b   = (const float*)d_in[15];
    float* out = (float*)d_out;

    char* ws = (char*)d_ws;
    size_t off = 0;
    auto alloc = [&](size_t nbytes) {
        void* p = ws + off; off += (nbytes + 255) & ~(size_t)255; return p;
    };
    unsigned short* xbf  = (unsigned short*)alloc((size_t)SQ * HH * 2);        // [0, 8.4M)
    unsigned short* qkvB = (unsigned short*)alloc((size_t)SQ * QKVW * 2);      // [8.4M, 33.6M)
    unsigned short* vtB  = (unsigned short*)alloc((size_t)NHEAD * HD * SQ * 2);// [33.6M, 41.9M)
    unsigned short* ctx  = (unsigned short*)alloc((size_t)SQ * HH * 2);        // [41.9M, 50.3M)
    float*          attn = (float*)alloc((size_t)SQ * HH * 4);                 // [50.3M, 67.1M)
    unsigned short* y    = (unsigned short*)alloc((size_t)SQ * HH * 2);        // [67.1M, 75.5M)
    unsigned short* hdn  = (unsigned short*)alloc((size_t)SQ * 4 * HH * 2);    // [75.5M, 109.1M)
    float*          extra = (float*)alloc((size_t)2 * SQ * HH * 4);            // [109.1M, 142.6M)

    const size_t PQ = (size_t)SQ * HH;      // floats per partial (16.8 MB)
    float* part = (float*)ws;               // partials overlap dead early buffers

    ln_kernel<<<SQ, 256, 0, stream>>>(hs, ln1g, ln1b, xbf);

    // QKV: M=2048,N=6144,K=2048. grid 48x16 = 768 blocks (3/CU); CH=8,CW=12.
    gemm128<2, 0><<<dim3(QKVW / 128, SQ / 128, 1), 256, 0, stream>>>(
        xbf, qkvw, qkvb, qkvB, vtB, nullptr, QKVW, HH, HH, HH, 8, 12);

    attn_kernel<<<512, 128, 0, stream>>>(qkvB, vtB, ctx);

    // dense: split-K x4 (16x16x4 = 1024 blocks, kLen=512 -> nt=8); CH=8,CW=16
    gemm128<0, 0><<<dim3(HH / 128, SQ / 128, 4), 256, 0, stream>>>(
        ctx, dw, nullptr, part, nullptr, hdn, HH, HH, HH, HH / 4, 8, 16);
    reduce4_kernel<<<2048, 256, 0, stream>>>(
        part, part + PQ, (float*)hdn, (float*)hdn + PQ, hs, db, attn, SQ * HH / 4, HH / 4 - 1);

    ln_kernel<<<SQ, 256, 0, stream>>>(attn, ln2g, ln2b, y);

    // FC1: M=2048,N=8192,K=2048. grid 64x16 = 1024 blocks (4/CU); CH=8,CW=16.
    gemm128<1, 1><<<dim3(4 * HH / 128, SQ / 128, 1), 256, 0, stream>>>(
        y, f1w, f1b, hdn, nullptr, nullptr, 4 * HH, HH, HH, HH, 8, 16);

    // FC2: split-K x4 (16x16x4 = 1024 blocks, kLen=2048 -> nt=32; 4*2048=8192=K)
    gemm128<0, 0><<<dim3(HH / 128, SQ / 128, 4), 256, 0, stream>>>(
        hdn, f2w, nullptr, part, nullptr, extra, HH, 4 * HH, 4 * HH, HH, 8, 16);
    reduce4_kernel<<<2048, 256, 0, stream>>>(
        part, part + PQ, extra, extra + PQ, attn, f2b, out, SQ * HH / 4, HH / 4 - 1);
}

// Round 13
// 469.240 us; speedup vs baseline: 1.5305x; 1.4727x over previous
//
#include <hip/hip_runtime.h>
#include <hip/hip_bf16.h>

#define SQ 2048
#define HH 2048
#define NHEAD 16
#define HD 128
#define QKVW (NHEAD*3*HD)   // 6144

typedef __attribute__((ext_vector_type(8))) short bf16x8;
typedef __attribute__((ext_vector_type(4))) float f32x4;
typedef __attribute__((ext_vector_type(16))) float f32x16;

__device__ inline unsigned short f2bf(float f) {
    union { float f; unsigned u; } x; x.f = f;
    unsigned r = x.u + 0x7FFFu + ((x.u >> 16) & 1u);
    return (unsigned short)(r >> 16);
}

__device__ inline unsigned pack_bf2(float a, float b) {
    return (unsigned)f2bf(a) | ((unsigned)f2bf(b) << 16);
}

__device__ inline float gelu_f(float x) {
    float x3 = x * (1.f + 0.044715f * x * x);
    return 0.5f * x * (1.f + tanhf(0.79788456f * x3));
}

// async global->LDS, 16B per lane. lds must be wave-uniform; g is per-lane.
__device__ inline void gld16(void* lds, const void* g) {
    __builtin_amdgcn_global_load_lds(
        (__attribute__((address_space(1))) void*)(g),
        (__attribute__((address_space(3))) void*)(lds), 16, 0, 0);
}

// ---------------- LayerNorm: fp32 in -> bf16 out ----------------
__global__ __launch_bounds__(256) void ln_kernel(
    const float* __restrict__ in, const float* __restrict__ g,
    const float* __restrict__ b, unsigned short* __restrict__ out)
{
    int row = blockIdx.x;
    int t = threadIdx.x, lane = t & 63, wid = t >> 6;
    const float4* rp = (const float4*)(in + (size_t)row * HH);
    float4 v0 = rp[t], v1 = rp[t + 256];
    float s  = v0.x + v0.y + v0.z + v0.w + v1.x + v1.y + v1.z + v1.w;
    float ss = v0.x*v0.x + v0.y*v0.y + v0.z*v0.z + v0.w*v0.w
             + v1.x*v1.x + v1.y*v1.y + v1.z*v1.z + v1.w*v1.w;
    #pragma unroll
    for (int o = 32; o; o >>= 1) { s += __shfl_down(s, o); ss += __shfl_down(ss, o); }
    __shared__ float r0[4], r1[4];
    if (lane == 0) { r0[wid] = s; r1[wid] = ss; }
    __syncthreads();
    s  = r0[0] + r0[1] + r0[2] + r0[3];
    ss = r1[0] + r1[1] + r1[2] + r1[3];
    float mu = s * (1.f / HH);
    float var = ss * (1.f / HH) - mu * mu;
    float rs = rsqrtf(var + 1e-5f);
    float4 g0 = ((const float4*)g)[t], g1 = ((const float4*)g)[t + 256];
    float4 b0 = ((const float4*)b)[t], b1 = ((const float4*)b)[t + 256];
    ushort4 o0, o1;
    o0.x = f2bf((v0.x - mu) * rs * g0.x + b0.x);
    o0.y = f2bf((v0.y - mu) * rs * g0.y + b0.y);
    o0.z = f2bf((v0.z - mu) * rs * g0.z + b0.z);
    o0.w = f2bf((v0.w - mu) * rs * g0.w + b0.w);
    o1.x = f2bf((v1.x - mu) * rs * g1.x + b1.x);
    o1.y = f2bf((v1.y - mu) * rs * g1.y + b1.y);
    o1.z = f2bf((v1.z - mu) * rs * g1.z + b1.z);
    o1.w = f2bf((v1.w - mu) * rs * g1.w + b1.w);
    ushort4* op = (ushort4*)(out + (size_t)row * HH);
    op[t] = o0; op[t + 256] = o1;
}

// ---------------- reduce: out = sum(4 partials) + res + bias ----------------
__global__ __launch_bounds__(256) void reduce4_kernel(
    const float* __restrict__ p0, const float* __restrict__ p1,
    const float* __restrict__ p2, const float* __restrict__ p3,
    const float* __restrict__ res, const float* __restrict__ bias,
    float* __restrict__ out, int n4, int nc4m1)
{
    int i = blockIdx.x * blockDim.x + threadIdx.x;
    int st = gridDim.x * blockDim.x;
    for (; i < n4; i += st) {
        float4 a = ((const float4*)p0)[i];
        float4 b = ((const float4*)p1)[i];
        float4 c = ((const float4*)p2)[i];
        float4 d = ((const float4*)p3)[i];
        float4 r = ((const float4*)res)[i];
        float4 bv = ((const float4*)bias)[i & nc4m1];
        float4 o;
        o.x = a.x + b.x + c.x + d.x + r.x + bv.x;
        o.y = a.y + b.y + c.y + d.y + r.y + bv.y;
        o.z = a.z + b.z + c.z + d.z + r.z + bv.z;
        o.w = a.w + b.w + c.w + d.w + r.w + bv.w;
        ((float4*)out)[i] = o;
    }
}

// ====== 256x128 GEMM, BK=32, 32x32x16 MFMA, 8 waves, 2 blocks/CU ======
// C[M,N] = A[M,K]bf16 @ B[N,K]fp32^T (converted in-kernel). 512 thr = 8 waves
// (2M x 4N); per-wave C 128x32 = 4 frags of 32x32 (f32x16, 64 acc VGPR).
// 8 MFMA/wave/tile (vs 16 @16x16): half the matrix-pipe instructions.
// LDS: Asm[2][256][32] linear (gld16, src chunk-XOR s(r)=(r>>1)&3 -> <=4-way
// read), Bsm[2][128][40] padded (fp32 reg-staged). 52 KiB -> 2 blocks/CU.
// Per K-tile: ds_write B(u+1) (regs); gld16 A(u+1); load B(u+2) fp32;
// compute tile u (32x32 frags); __syncthreads().

// MODE: 0 = fp32 partial (no bias), 1 = bf16 + bias (+GELU), 2 = QKV splitV
template<int MODE, int GELU_ON>
__global__ __launch_bounds__(512, 4) void gemm256(
    const unsigned short* __restrict__ A, const float* __restrict__ B,
    const float* __restrict__ bias, void* __restrict__ outp,
    unsigned short* __restrict__ vtb, void* __restrict__ outp_hi,
    int N, int lda, int ldb, int kLen, int CH, int CW)
{
    __shared__ __align__(16) unsigned short Asm[2][256][32];   // 32 KiB
    __shared__ __align__(16) unsigned short Bsm[2][128][40];   // 20 KiB

    int t = threadIdx.x, lane = t & 63, wid = t >> 6;
    int l32 = lane & 31, h2 = lane >> 5;
    int wr = wid >> 2, wc = wid & 3;

    // 2D chunked XCD swizzle over (R = bz*gy+by, bx); CHxCW rectangle per XCD.
    int id = (blockIdx.z * gridDim.y + blockIdx.y) * gridDim.x + blockIdx.x;
    int xcd = id & 7, local = id >> 3;
    int cgx = gridDim.x / CW;
    int cr = xcd / cgx, cc = xcd - cr * cgx;
    int lr = local / CW, lc = local - lr * CW;
    int R  = cr * CH + lr;
    int bn = cc * CW + lc;
    int bm = R % gridDim.y;
    int bz = R / gridDim.y;
    int m0 = bm * 256, n0 = bn * 128;
    int kstart = bz * kLen;
    int nt = kLen >> 5;                     // BK = 32

    // A staging: 2 gld16/thread; call j covers rows wid*32 + j*16 + (lane>>2).
    int r0_ = wid * 32 + (lane >> 2);
    int r1_ = r0_ + 16;
    const unsigned short* Abase = A + (size_t)m0 * lda + kstart;
    const unsigned short* Asrc0 = Abase + (size_t)r0_ * lda
                                + (((lane & 3) ^ ((r0_ >> 1) & 3)) << 3);
    const unsigned short* Asrc1 = Abase + (size_t)r1_ * lda
                                + (((lane & 3) ^ ((r1_ >> 1) & 3)) << 3);
    // B staging: thread t -> row t>>2, chunk t&3 (8 fp32 -> 16B bf16).
    int rB = t >> 2, cB = t & 3;
    const float* Bsrc = B + (size_t)(n0 + rB) * ldb + kstart + cB * 8;

    // ---- prologue: A(0) in flight; Bs[0]<-B(0); p = B(1)
    gld16(&Asm[0][wid * 32][0], Asrc0);
    gld16(&Asm[0][wid * 32 + 16][0], Asrc1);
    {
        float4 q0 = *(const float4*)(Bsrc);
        float4 q1 = *(const float4*)(Bsrc + 4);
        int4 w;
        w.x = (int)pack_bf2(q0.x, q0.y); w.y = (int)pack_bf2(q0.z, q0.w);
        w.z = (int)pack_bf2(q1.x, q1.y); w.w = (int)pack_bf2(q1.z, q1.w);
        *(int4*)&Bsm[0][rB][cB * 8] = w;
    }
    int k1 = (nt > 1) ? 32 : 0;
    float4 p0_ = *(const float4*)(Bsrc + k1);
    float4 p1_ = *(const float4*)(Bsrc + k1 + 4);
    __syncthreads();

    f32x16 acc[4] = {};
    for (int u = 0; u < nt; u++) {
        int buf = u & 1, nbuf = buf ^ 1;
        int t1 = ((u + 1 < nt) ? u + 1 : nt - 1) * 32;
        int t2 = ((u + 2 < nt) ? u + 2 : nt - 1) * 32;
        // write B(u+1) (p regs, drained by last barrier) -> Bsm[nbuf]
        {
            int4 w;
            w.x = (int)pack_bf2(p0_.x, p0_.y); w.y = (int)pack_bf2(p0_.z, p0_.w);
            w.z = (int)pack_bf2(p1_.x, p1_.y); w.w = (int)pack_bf2(p1_.z, p1_.w);
            *(int4*)&Bsm[nbuf][rB][cB * 8] = w;
        }
        // stage A(u+1)
        gld16(&Asm[nbuf][wid * 32][0], Asrc0 + t1);
        gld16(&Asm[nbuf][wid * 32 + 16][0], Asrc1 + t1);
        // load B(u+2) -> p
        p0_ = *(const float4*)(Bsrc + t2);
        p1_ = *(const float4*)(Bsrc + t2 + 4);
        // compute tile u (32x32x16 MFMA; first operand = B (N-dim rows))
        __builtin_amdgcn_s_setprio(1);
        #pragma unroll
        for (int ks = 0; ks < 2; ks++) {
            bf16x8 bfr = *(const bf16x8*)&Bsm[buf][wc * 32 + l32][ks * 16 + h2 * 8];
            #pragma unroll
            for (int fi = 0; fi < 4; fi++) {
                int r = wr * 128 + fi * 32 + l32;
                bf16x8 af = *(const bf16x8*)
                    &Asm[buf][r][(((ks * 2 + h2) ^ ((r >> 1) & 3))) << 3];
                acc[fi] = __builtin_amdgcn_mfma_f32_32x32x16_bf16(bfr, af, acc[fi], 0, 0, 0);
            }
        }
        __builtin_amdgcn_s_setprio(0);
        __syncthreads();
    }

    // ---- epilogue ----  32x32 C/D layout (operand-swapped):
    //   m = m0 + wr*128 + fi*32 + l32
    //   n = n0 + wc*32 + g*8 + h2*4 + j    (acc[fi][g*4+j], j contiguous in N)
    if (MODE == 0) {
        float* po = ((bz < 2) ? (float*)outp : (float*)outp_hi)
                  + (size_t)(bz & 1) * SQ * (size_t)N;
        #pragma unroll
        for (int fi = 0; fi < 4; fi++) {
            int gr = m0 + wr * 128 + fi * 32 + l32;
            #pragma unroll
            for (int g = 0; g < 4; g++) {
                int gc = n0 + wc * 32 + g * 8 + h2 * 4;
                float4 v;
                v.x = acc[fi][g*4+0]; v.y = acc[fi][g*4+1];
                v.z = acc[fi][g*4+2]; v.w = acc[fi][g*4+3];
                *(float4*)&po[(size_t)gr * N + gc] = v;
            }
        }
    } else if (MODE == 1) {
        unsigned short* op = (unsigned short*)outp;
        #pragma unroll
        for (int fi = 0; fi < 4; fi++) {
            int gr = m0 + wr * 128 + fi * 32 + l32;
            #pragma unroll
            for (int g = 0; g < 4; g++) {
                int gc = n0 + wc * 32 + g * 8 + h2 * 4;
                float4 bi = *(const float4*)&bias[gc];
                float v0 = acc[fi][g*4+0] + bi.x, v1 = acc[fi][g*4+1] + bi.y;
                float v2 = acc[fi][g*4+2] + bi.z, v3 = acc[fi][g*4+3] + bi.w;
                if (GELU_ON) { v0 = gelu_f(v0); v1 = gelu_f(v1); v2 = gelu_f(v2); v3 = gelu_f(v3); }
                ushort4 o; o.x = f2bf(v0); o.y = f2bf(v1); o.z = f2bf(v2); o.w = f2bf(v3);
                *(ushort4*)&op[(size_t)gr * N + gc] = o;
            }
        }
    } else {
        // QKV: tile (128 cols) is entirely q, k, or v of head n0/384
        unsigned short* op = (unsigned short*)outp;
        int head = n0 / 384;
        int cat = (n0 >> 7) % 3;
        #pragma unroll
        for (int fi = 0; fi < 4; fi++) {
            int gr = m0 + wr * 128 + fi * 32 + l32;
            #pragma unroll
            for (int g = 0; g < 4; g++) {
                int gc = n0 + wc * 32 + g * 8 + h2 * 4;
                float4 bi = *(const float4*)&bias[gc];
                float v0 = acc[fi][g*4+0] + bi.x, v1 = acc[fi][g*4+1] + bi.y;
                float v2 = acc[fi][g*4+2] + bi.z, v3 = acc[fi][g*4+3] + bi.w;
                if (cat == 2) {             // V columns -> transposed store
                    int d = wc * 32 + g * 8 + h2 * 4;
                    unsigned short* vp = vtb + (size_t)(head * HD + d) * SQ + gr;
                    vp[0]      = f2bf(v0);
                    vp[SQ]     = f2bf(v1);
                    vp[2 * SQ] = f2bf(v2);
                    vp[3 * SQ] = f2bf(v3);
                } else {
                    ushort4 o; o.x = f2bf(v0); o.y = f2bf(v1); o.z = f2bf(v2); o.w = f2bf(v3);
                    *(ushort4*)&op[(size_t)gr * N + gc] = o;
                }
            }
        }
    }
}

// ---------------- Flash attention: 32x32 MFMA, causal + alibi ----------------
__global__ __launch_bounds__(128) void attn_kernel(
    const unsigned short* __restrict__ qkvB,  // [S][6144] bf16 (q,k valid)
    const unsigned short* __restrict__ vtb,   // [NH][HD][S] bf16
    unsigned short* __restrict__ ctx)         // [S][2048] bf16
{
    int w = blockIdx.x;
    int lid = (w & 7) * 64 + (w >> 3);
    int n = lid >> 5, qt = lid & 31;
    int t = threadIdx.x, lane = t & 63, wid = t >> 6;
    int l32 = lane & 31, h2 = lane >> 5;
    int q0 = qt * 64, qg = q0 + wid * 32 + l32;

    __shared__ __align__(16) unsigned short Ks[64][128];
    __shared__ __align__(16) unsigned short Vt[128][64];

    bf16x8 qf[8];
    const unsigned short* qp = qkvB + (size_t)qg * QKVW + n * 384 + h2 * 8;
    #pragma unroll
    for (int d8 = 0; d8 < 8; d8++)
        qf[d8] = *(const bf16x8*)(qp + d8 * 16);

    const float slope = exp2f(-0.5f * (float)(n + 1));
    const float inv = 0.08838834764831845f;   // 1/sqrt(128)
    float m = -INFINITY, lsum = 0.f;
    f32x16 ao[4] = {};

    int krow = lane >> 4, kch = lane & 15;
    int vrow = lane >> 3, vch = lane & 7;
    const unsigned short* kb_ = qkvB + n * 384 + 128;
    const unsigned short* vb_ = vtb + (size_t)n * HD * SQ;
    const char* ksb = (const char*)&Ks[0][0];
    const char* vsb = (const char*)&Vt[0][0];

    int nkb = qt + 1;
    for (int kb = 0; kb < nkb; kb++) {
        int k0 = kb * 64;
        __syncthreads();
        #pragma unroll
        for (int s = 0; s < 8; s++) {
            int r = wid * 32 + s * 4 + krow;
            gld16(&Ks[wid * 32 + s * 4][0],
                  kb_ + (size_t)(k0 + r) * QKVW + ((kch ^ (r & 7)) << 3));
            int dd = wid * 64 + s * 8 + vrow;
            gld16(&Vt[wid * 64 + s * 8][0],
                  vb_ + (size_t)dd * SQ + k0 + ((vch ^ (dd & 7)) << 3));
        }
        __syncthreads();

        f32x16 sc0 = {}, sc1 = {};
        #pragma unroll
        for (int d8 = 0; d8 < 8; d8++) {
            int ch = ((d8 * 2 + h2) ^ (l32 & 7)) << 4;
            bf16x8 kf0 = *(const bf16x8*)(ksb + l32 * 256 + ch);
            bf16x8 kf1 = *(const bf16x8*)(ksb + (32 + l32) * 256 + ch);
            sc0 = __builtin_amdgcn_mfma_f32_32x32x16_bf16(kf0, qf[d8], sc0, 0, 0, 0);
            sc1 = __builtin_amdgcn_mfma_f32_32x32x16_bf16(kf1, qf[d8], sc1, 0, 0, 0);
        }

        float tmax = -INFINITY;
        int last = (kb == nkb - 1);
        #pragma unroll
        for (int r = 0; r < 16; r++) {
            int kl = (r & 3) + 8 * (r >> 2) + 4 * h2;
            float s0 = sc0[r] * inv + slope * (float)(k0 + kl);
            float s1 = sc1[r] * inv + slope * (float)(k0 + 32 + kl);
            if (last) {
                if (k0 + kl > qg) s0 = -INFINITY;
                if (k0 + 32 + kl > qg) s1 = -INFINITY;
            }
            sc0[r] = s0; sc1[r] = s1;
            tmax = fmaxf(tmax, fmaxf(s0, s1));
        }
        tmax = fmaxf(tmax, __shfl_xor(tmax, 32));
        if (!__all(tmax <= m + 8.f)) {          // defer-max (T13)
            float mnew = fmaxf(m, tmax);
            float sca = __expf(m - mnew);
            m = mnew;
            lsum *= sca;
            #pragma unroll
            for (int db = 0; db < 4; db++)
                #pragma unroll
                for (int e = 0; e < 16; e++) ao[db][e] *= sca;
        }
        float psum = 0.f;
        #pragma unroll
        for (int r = 0; r < 16; r++) {
            sc0[r] = __expf(sc0[r] - m); psum += sc0[r];
            sc1[r] = __expf(sc1[r] - m); psum += sc1[r];
        }
        psum += __shfl_xor(psum, 32);
        lsum += psum;

        #pragma unroll
        for (int kstep = 0; kstep < 4; kstep++) {
            const int ks1 = kstep & 1;
            float a0, a1, a2, a3, b0, b1, b2, b3;
            if (kstep < 2) {
                a0 = sc0[8*ks1+0]; a1 = sc0[8*ks1+1]; a2 = sc0[8*ks1+2]; a3 = sc0[8*ks1+3];
                b0 = sc0[8*ks1+4]; b1 = sc0[8*ks1+5]; b2 = sc0[8*ks1+6]; b3 = sc0[8*ks1+7];
            } else {
                a0 = sc1[8*ks1+0]; a1 = sc1[8*ks1+1]; a2 = sc1[8*ks1+2]; a3 = sc1[8*ks1+3];
                b0 = sc1[8*ks1+4]; b1 = sc1[8*ks1+5]; b2 = sc1[8*ks1+6]; b3 = sc1[8*ks1+7];
            }
            unsigned ku0 = pack_bf2(h2 ? b0 : a0, h2 ? b1 : a1);
            unsigned ku1 = pack_bf2(h2 ? b2 : a2, h2 ? b3 : a3);
            unsigned su0 = pack_bf2(h2 ? a0 : b0, h2 ? a1 : b1);
            unsigned su1 = pack_bf2(h2 ? a2 : b2, h2 ? a3 : b3);
            unsigned r0 = (unsigned)__shfl_xor((int)su0, 32);
            unsigned r1 = (unsigned)__shfl_xor((int)su1, 32);
            union { int4 i; bf16x8 v; } u;
            u.i.x = h2 ? (int)r0  : (int)ku0;
            u.i.y = h2 ? (int)r1  : (int)ku1;
            u.i.z = h2 ? (int)ku0 : (int)r0;
            u.i.w = h2 ? (int)ku1 : (int)r1;
            bf16x8 pf = u.v;
            int ch = ((kstep * 2 + h2) ^ (l32 & 7)) << 4;
            #pragma unroll
            for (int db = 0; db < 4; db++) {
                bf16x8 vf = *(const bf16x8*)(vsb + (db * 32 + l32) * 128 + ch);
                ao[db] = __builtin_amdgcn_mfma_f32_32x32x16_bf16(vf, pf, ao[db], 0, 0, 0);
            }
        }
    }

    float rl = 1.f / lsum;
    #pragma unroll
    for (int db = 0; db < 4; db++)
        #pragma unroll
        for (int g = 0; g < 4; g++) {
            ushort4 o;
            o.x = f2bf(ao[db][g*4+0] * rl);
            o.y = f2bf(ao[db][g*4+1] * rl);
            o.z = f2bf(ao[db][g*4+2] * rl);
            o.w = f2bf(ao[db][g*4+3] * rl);
            *(ushort4*)(ctx + (size_t)qg * HH + n * HD + db * 32 + g * 8 + h2 * 4) = o;
        }
}

extern "C" void kernel_launch(void* const* d_in, const int* in_sizes, int n_in,
                              void* d_out, int out_size, void* d_ws, size_t ws_size,
                              hipStream_t stream) {
    const float* hs    = (const float*)d_in[0];
    const float* ln1g  = (const float*)d_in[4];
    const float* ln1b  = (const float*)d_in[5];
    const float* qkvw  = (const float*)d_in[6];
    const float* qkvb  = (const float*)d_in[7];
    const float* dw    = (const float*)d_in[8];
    const float* db    = (const float*)d_in[9];
    const float* ln2g  = (const float*)d_in[10];
    const float* ln2b  = (const float*)d_in[11];
    const float* f1w   = (const float*)d_in[12];
    const float* f1b   = (const float*)d_in[13];
    const float* f2w   = (const float*)d_in[14];
    const float* f2b   = (const float*)d_in[15];
    float* out = (float*)d_out;

    char* ws = (char*)d_ws;
    size_t off = 0;
    auto alloc = [&](size_t nbytes) {
        void* p = ws + off; off += (nbytes + 255) & ~(size_t)255; return p;
    };
    unsigned short* xbf  = (unsigned short*)alloc((size_t)SQ * HH * 2);        // [0, 8.4M)
    unsigned short* qkvB = (unsigned short*)alloc((size_t)SQ * QKVW * 2);      // [8.4M, 33.6M)
    unsigned short* vtB  = (unsigned short*)alloc((size_t)NHEAD * HD * SQ * 2);// [33.6M, 41.9M)
    unsigned short* ctx  = (unsigned short*)alloc((size_t)SQ * HH * 2);        // [41.9M, 50.3M)
    float*          attn = (float*)alloc((size_t)SQ * HH * 4);                 // [50.3M, 67.1M)
    unsigned short* y    = (unsigned short*)alloc((size_t)SQ * HH * 2);        // [67.1M, 75.5M)
    unsigned short* hdn  = (unsigned short*)alloc((size_t)SQ * 4 * HH * 2);    // [75.5M, 109.1M)
    float*          extra = (float*)alloc((size_t)2 * SQ * HH * 4);            // [109.1M, 142.6M)

    const size_t PQ = (size_t)SQ * HH;      // floats per partial (16.8 MB)
    float* part = (float*)ws;               // partials overlap dead early buffers

    ln_kernel<<<SQ, 256, 0, stream>>>(hs, ln1g, ln1b, xbf);

    // QKV: M=2048,N=6144,K=2048. grid 48x8 = 384 blocks; CH=4,CW=12.
    gemm256<2, 0><<<dim3(QKVW / 128, SQ / 256, 1), 512, 0, stream>>>(
        xbf, qkvw, qkvb, qkvB, vtB, nullptr, QKVW, HH, HH, HH, 4, 12);

    attn_kernel<<<512, 128, 0, stream>>>(qkvB, vtB, ctx);

    // dense: split-K x4 (16x8x4 = 512 blocks, kLen=512); CH=8,CW=8
    gemm256<0, 0><<<dim3(HH / 128, SQ / 256, 4), 512, 0, stream>>>(
        ctx, dw, nullptr, part, nullptr, hdn, HH, HH, HH, HH / 4, 8, 8);
    reduce4_kernel<<<2048, 256, 0, stream>>>(
        part, part + PQ, (float*)hdn, (float*)hdn + PQ, hs, db, attn, SQ * HH / 4, HH / 4 - 1);

    ln_kernel<<<SQ, 256, 0, stream>>>(attn, ln2g, ln2b, y);

    // FC1: M=2048,N=8192,K=2048. grid 64x8 = 512 blocks; CH=4,CW=16.
    gemm256<1, 1><<<dim3(4 * HH / 128, SQ / 256, 1), 512, 0, stream>>>(
        y, f1w, f1b, hdn, nullptr, nullptr, 4 * HH, HH, HH, HH, 4, 16);

    // FC2: split-K x4 (16x8x4 = 512 blocks, kLen=2048; 4*2048=8192=K); CH=8,CW=8
    gemm256<0, 0><<<dim3(HH / 128, SQ / 256, 4), 512, 0, stream>>>(
        hdn, f2w, nullptr, part, nullptr, extra, HH, 4 * HH, 4 * HH, HH, 8, 8);
    reduce4_kernel<<<2048, 256, 0, stream>>>(
        part, part + PQ, extra, extra + PQ, attn, f2b, out, SQ * HH / 4, HH / 4 - 1);
}

// Round 15
// 446.176 us; speedup vs baseline: 1.6096x; 1.0517x over previous
//
#include <hip/hip_runtime.h>
#include <hip/hip_bf16.h>

#define SQ 2048
#define HH 2048
#define NHEAD 16
#define HD 128
#define QKVW (NHEAD*3*HD)   // 6144

typedef __attribute__((ext_vector_type(8))) short bf16x8;
typedef __attribute__((ext_vector_type(4))) float f32x4;
typedef __attribute__((ext_vector_type(16))) float f32x16;

__device__ inline unsigned short f2bf(float f) {
    union { float f; unsigned u; } x; x.f = f;
    unsigned r = x.u + 0x7FFFu + ((x.u >> 16) & 1u);
    return (unsigned short)(r >> 16);
}

__device__ inline unsigned pack_bf2(float a, float b) {
    return (unsigned)f2bf(a) | ((unsigned)f2bf(b) << 16);
}

__device__ inline float gelu_f(float x) {
    float x3 = x * (1.f + 0.044715f * x * x);
    return 0.5f * x * (1.f + tanhf(0.79788456f * x3));
}

// async global->LDS, 16B per lane. lds must be wave-uniform; g is per-lane.
__device__ inline void gld16(void* lds, const void* g) {
    __builtin_amdgcn_global_load_lds(
        (__attribute__((address_space(1))) void*)(g),
        (__attribute__((address_space(3))) void*)(lds), 16, 0, 0);
}

// ---------------- fp32 -> bf16 convert ----------------
__global__ __launch_bounds__(256) void cvt_kernel(
    const float* __restrict__ in, unsigned short* __restrict__ out, int n4)
{
    int i = blockIdx.x * blockDim.x + threadIdx.x;
    int stride = gridDim.x * blockDim.x;
    for (; i < n4; i += stride) {
        float4 f = ((const float4*)in)[i];
        ushort4 o;
        o.x = f2bf(f.x); o.y = f2bf(f.y); o.z = f2bf(f.z); o.w = f2bf(f.w);
        ((ushort4*)out)[i] = o;
    }
}

// ---------------- LayerNorm: fp32 in -> bf16 out ----------------
__global__ __launch_bounds__(256) void ln_kernel(
    const float* __restrict__ in, const float* __restrict__ g,
    const float* __restrict__ b, unsigned short* __restrict__ out)
{
    int row = blockIdx.x;
    int t = threadIdx.x, lane = t & 63, wid = t >> 6;
    const float4* rp = (const float4*)(in + (size_t)row * HH);
    float4 v0 = rp[t], v1 = rp[t + 256];
    float s  = v0.x + v0.y + v0.z + v0.w + v1.x + v1.y + v1.z + v1.w;
    float ss = v0.x*v0.x + v0.y*v0.y + v0.z*v0.z + v0.w*v0.w
             + v1.x*v1.x + v1.y*v1.y + v1.z*v1.z + v1.w*v1.w;
    #pragma unroll
    for (int o = 32; o; o >>= 1) { s += __shfl_down(s, o); ss += __shfl_down(ss, o); }
    __shared__ float r0[4], r1[4];
    if (lane == 0) { r0[wid] = s; r1[wid] = ss; }
    __syncthreads();
    s  = r0[0] + r0[1] + r0[2] + r0[3];
    ss = r1[0] + r1[1] + r1[2] + r1[3];
    float mu = s * (1.f / HH);
    float var = ss * (1.f / HH) - mu * mu;
    float rs = rsqrtf(var + 1e-5f);
    float4 g0 = ((const float4*)g)[t], g1 = ((const float4*)g)[t + 256];
    float4 b0 = ((const float4*)b)[t], b1 = ((const float4*)b)[t + 256];
    ushort4 o0, o1;
    o0.x = f2bf((v0.x - mu) * rs * g0.x + b0.x);
    o0.y = f2bf((v0.y - mu) * rs * g0.y + b0.y);
    o0.z = f2bf((v0.z - mu) * rs * g0.z + b0.z);
    o0.w = f2bf((v0.w - mu) * rs * g0.w + b0.w);
    o1.x = f2bf((v1.x - mu) * rs * g1.x + b1.x);
    o1.y = f2bf((v1.y - mu) * rs * g1.y + b1.y);
    o1.z = f2bf((v1.z - mu) * rs * g1.z + b1.z);
    o1.w = f2bf((v1.w - mu) * rs * g1.w + b1.w);
    ushort4* op = (ushort4*)(out + (size_t)row * HH);
    op[t] = o0; op[t + 256] = o1;
}

// ---------------- reduce: out = sum(NP partials) + res + bias ----------------
template<int NP>
__global__ __launch_bounds__(256) void reduceN_kernel(
    const float* __restrict__ p0, const float* __restrict__ p1,
    const float* __restrict__ p2, const float* __restrict__ p3,
    const float* __restrict__ res, const float* __restrict__ bias,
    float* __restrict__ out, int n4, int nc4m1)
{
    int i = blockIdx.x * blockDim.x + threadIdx.x;
    int st = gridDim.x * blockDim.x;
    for (; i < n4; i += st) {
        float4 a = ((const float4*)p0)[i];
        float4 b = ((const float4*)p1)[i];
        float4 r = ((const float4*)res)[i];
        float4 bv = ((const float4*)bias)[i & nc4m1];
        float4 o;
        o.x = a.x + b.x + r.x + bv.x;
        o.y = a.y + b.y + r.y + bv.y;
        o.z = a.z + b.z + r.z + bv.z;
        o.w = a.w + b.w + r.w + bv.w;
        if (NP >= 3) {
            float4 c = ((const float4*)p2)[i];
            o.x += c.x; o.y += c.y; o.z += c.z; o.w += c.w;
        }
        if (NP >= 4) {
            float4 d = ((const float4*)p3)[i];
            o.x += d.x; o.y += d.y; o.z += d.z; o.w += d.w;
        }
        ((float4*)out)[i] = o;
    }
}

// ====== 128x128 GEMM, BK=32, bf16 A&B via gld16, 4 blocks/CU ======
// C[M,N] = A[M,K]bf16 @ B[N,K]bf16^T. 256 thr = 4 waves (2M x 2N);
// per-wave C 64x64 (4x4 16x16 frags). LDS 2buf x (A 8KB + B 8KB) = 32 KiB
// -> 4 blocks/CU. 16 KB staged/iter.
// Tests the empirical law: per-block staging ~13.4 B/cyc, per-CU throughput
// = blocks/CU x per-block rate.
// Loop: {stage A,B(u+1)->buf^1 (4 gld16); compute u from buf; sync}.

// MODE: 0 = fp32 partial (no bias), 1 = bf16 + bias (+GELU), 2 = QKV splitV
template<int MODE, int GELU_ON>
__global__ __launch_bounds__(256, 4) void gemm128(
    const unsigned short* __restrict__ A, const unsigned short* __restrict__ B,
    const float* __restrict__ bias, void* __restrict__ outp,
    unsigned short* __restrict__ vtb, void* __restrict__ outp_hi,
    int N, int lda, int ldb, int kLen, int Ktot, int CH, int CW)
{
    __shared__ __align__(16) unsigned short Asm[2][128][32];   // 16 KiB
    __shared__ __align__(16) unsigned short Bsm[2][128][32];   // 16 KiB

    int t = threadIdx.x, lane = t & 63, wid = t >> 6;
    int lo = lane & 15, hi = lane >> 4;
    int wr = wid >> 1, wc = wid & 1;

    // 2D chunked XCD swizzle over (R = bz*gy+by, bx); CHxCW rectangle per XCD.
    int id = (blockIdx.z * gridDim.y + blockIdx.y) * gridDim.x + blockIdx.x;
    int xcd = id & 7, local = id >> 3;
    int cgx = gridDim.x / CW;
    int cr = xcd / cgx, cc = xcd - cr * cgx;
    int lr = local / CW, lc = local - lr * CW;
    int R  = cr * CH + lr;
    int bn = cc * CW + lc;
    int bm = R % gridDim.y;
    int bz = R / gridDim.y;
    int m0 = bm * 128, n0 = bn * 128;
    int kstart = bz * kLen;
    int rem = Ktot - kstart;
    int nt = ((rem < kLen) ? rem : kLen) >> 5;   // BK = 32

    // Staging: per thread 2 A-chunks + 2 B-chunks (16B each).
    // thread t -> row (t>>2) and 64+(t>>2), chunk t&3; src chunk XOR (row&3).
    int rS = t >> 2, cS = t & 3;
    int sc0_ = (cS ^ (rS & 3)) << 3;        // (64+rS)&3 == rS&3
    const unsigned short* Ab = A + (size_t)m0 * lda + kstart;
    const unsigned short* Bb = B + (size_t)n0 * ldb + kstart;
    const unsigned short* Asrc0 = Ab + (size_t)rS * lda + sc0_;
    const unsigned short* Asrc1 = Ab + (size_t)(64 + rS) * lda + sc0_;
    const unsigned short* Bsrc0 = Bb + (size_t)rS * ldb + sc0_;
    const unsigned short* Bsrc1 = Bb + (size_t)(64 + rS) * ldb + sc0_;

    // prologue: tile 0 -> buf 0
    gld16(&Asm[0][wid * 16][0], Asrc0);
    gld16(&Asm[0][64 + wid * 16][0], Asrc1);
    gld16(&Bsm[0][wid * 16][0], Bsrc0);
    gld16(&Bsm[0][64 + wid * 16][0], Bsrc1);
    __syncthreads();

    f32x4 acc[4][4] = {};
    for (int u = 0; u < nt; u++) {
        int buf = u & 1, nbuf = buf ^ 1;
        int t1 = ((u + 1 < nt) ? u + 1 : nt - 1) * 32;
        // stage next tile (drains at end-of-iter barrier; overlaps compute)
        gld16(&Asm[nbuf][wid * 16][0], Asrc0 + t1);
        gld16(&Asm[nbuf][64 + wid * 16][0], Asrc1 + t1);
        gld16(&Bsm[nbuf][wid * 16][0], Bsrc0 + t1);
        gld16(&Bsm[nbuf][64 + wid * 16][0], Bsrc1 + t1);
        // compute tile u
        __builtin_amdgcn_s_setprio(1);
        {
            bf16x8 af[4], bfr[4];
            #pragma unroll
            for (int i = 0; i < 4; i++) {
                int r = wr * 64 + i * 16 + lo;
                af[i] = *(const bf16x8*)&Asm[buf][r][(hi ^ (r & 3)) << 3];
            }
            #pragma unroll
            for (int c = 0; c < 4; c++) {
                int r = wc * 64 + c * 16 + lo;
                bfr[c] = *(const bf16x8*)&Bsm[buf][r][(hi ^ (r & 3)) << 3];
            }
            #pragma unroll
            for (int i = 0; i < 4; i++)
                #pragma unroll
                for (int c = 0; c < 4; c++)
                    acc[i][c] = __builtin_amdgcn_mfma_f32_16x16x32_bf16(
                        bfr[c], af[i], acc[i][c], 0, 0, 0);
        }
        __builtin_amdgcn_s_setprio(0);
        __syncthreads();
    }

    // ---- epilogue ----  acc[i][c][j]: row M = m0+wr*64+i*16+lo,
    //                     col N = n0+wc*64+c*16+hi*4+j (j contiguous in N)
    if (MODE == 0) {
        float* po;
        if (bz == 0)      po = (float*)outp;
        else if (bz == 1) po = (float*)outp + (size_t)SQ * N;
        else if (bz == 2) po = (float*)outp_hi;
        else              po = (float*)vtb;
        #pragma unroll
        for (int i = 0; i < 4; i++) {
            int gr = m0 + wr * 64 + i * 16 + lo;
            #pragma unroll
            for (int c = 0; c < 4; c++) {
                int gc = n0 + wc * 64 + c * 16 + hi * 4;
                *(f32x4*)&po[(size_t)gr * N + gc] = acc[i][c];
            }
        }
    } else if (MODE == 1) {
        unsigned short* op = (unsigned short*)outp;
        #pragma unroll
        for (int i = 0; i < 4; i++) {
            int gr = m0 + wr * 64 + i * 16 + lo;
            #pragma unroll
            for (int c = 0; c < 4; c++) {
                int gc = n0 + wc * 64 + c * 16 + hi * 4;
                float4 bi = *(const float4*)&bias[gc];
                float v0 = acc[i][c][0] + bi.x, v1 = acc[i][c][1] + bi.y;
                float v2 = acc[i][c][2] + bi.z, v3 = acc[i][c][3] + bi.w;
                if (GELU_ON) { v0 = gelu_f(v0); v1 = gelu_f(v1); v2 = gelu_f(v2); v3 = gelu_f(v3); }
                ushort4 o; o.x = f2bf(v0); o.y = f2bf(v1); o.z = f2bf(v2); o.w = f2bf(v3);
                *(ushort4*)&op[(size_t)gr * N + gc] = o;
            }
        }
    } else {
        // QKV: tile (128 cols) is entirely q, k, or v of head n0/384
        unsigned short* op = (unsigned short*)outp;
        int head = n0 / 384;
        int cat = (n0 >> 7) % 3;
        #pragma unroll
        for (int i = 0; i < 4; i++) {
            int gr = m0 + wr * 64 + i * 16 + lo;
            #pragma unroll
            for (int c = 0; c < 4; c++) {
                int gc = n0 + wc * 64 + c * 16 + hi * 4;
                float4 bi = *(const float4*)&bias[gc];
                float v0 = acc[i][c][0] + bi.x, v1 = acc[i][c][1] + bi.y;
                float v2 = acc[i][c][2] + bi.z, v3 = acc[i][c][3] + bi.w;
                if (cat == 2) {             // V columns -> transposed store
                    int d = wc * 64 + c * 16 + hi * 4;
                    unsigned short* vp = vtb + (size_t)(head * HD + d) * SQ + gr;
                    vp[0]      = f2bf(v0);
                    vp[SQ]     = f2bf(v1);
                    vp[2 * SQ] = f2bf(v2);
                    vp[3 * SQ] = f2bf(v3);
                } else {
                    ushort4 o; o.x = f2bf(v0); o.y = f2bf(v1); o.z = f2bf(v2); o.w = f2bf(v3);
                    *(ushort4*)&op[(size_t)gr * N + gc] = o;
                }
            }
        }
    }
}

// ---------------- Flash attention: 32x32 MFMA, causal + alibi ----------------
__global__ __launch_bounds__(128) void attn_kernel(
    const unsigned short* __restrict__ qkvB,  // [S][6144] bf16 (q,k valid)
    const unsigned short* __restrict__ vtb,   // [NH][HD][S] bf16
    unsigned short* __restrict__ ctx)         // [S][2048] bf16
{
    int w = blockIdx.x;
    int lid = (w & 7) * 64 + (w >> 3);
    int n = lid >> 5, qt = lid & 31;
    int t = threadIdx.x, lane = t & 63, wid = t >> 6;
    int l32 = lane & 31, h2 = lane >> 5;
    int q0 = qt * 64, qg = q0 + wid * 32 + l32;

    __shared__ __align__(16) unsigned short Ks[64][128];
    __shared__ __align__(16) unsigned short Vt[128][64];

    bf16x8 qf[8];
    const unsigned short* qp = qkvB + (size_t)qg * QKVW + n * 384 + h2 * 8;
    #pragma unroll
    for (int d8 = 0; d8 < 8; d8++)
        qf[d8] = *(const bf16x8*)(qp + d8 * 16);

    const float slope = exp2f(-0.5f * (float)(n + 1));
    const float inv = 0.08838834764831845f;   // 1/sqrt(128)
    float m = -INFINITY, lsum = 0.f;
    f32x16 ao[4] = {};

    int krow = lane >> 4, kch = lane & 15;
    int vrow = lane >> 3, vch = lane & 7;
    const unsigned short* kb_ = qkvB + n * 384 + 128;
    const unsigned short* vb_ = vtb + (size_t)n * HD * SQ;
    const char* ksb = (const char*)&Ks[0][0];
    const char* vsb = (const char*)&Vt[0][0];

    int nkb = qt + 1;
    for (int kb = 0; kb < nkb; kb++) {
        int k0 = kb * 64;
        __syncthreads();
        #pragma unroll
        for (int s = 0; s < 8; s++) {
            int r = wid * 32 + s * 4 + krow;
            gld16(&Ks[wid * 32 + s * 4][0],
                  kb_ + (size_t)(k0 + r) * QKVW + ((kch ^ (r & 7)) << 3));
            int dd = wid * 64 + s * 8 + vrow;
            gld16(&Vt[wid * 64 + s * 8][0],
                  vb_ + (size_t)dd * SQ + k0 + ((vch ^ (dd & 7)) << 3));
        }
        __syncthreads();

        f32x16 sc0 = {}, sc1 = {};
        #pragma unroll
        for (int d8 = 0; d8 < 8; d8++) {
            int ch = ((d8 * 2 + h2) ^ (l32 & 7)) << 4;
            bf16x8 kf0 = *(const bf16x8*)(ksb + l32 * 256 + ch);
            bf16x8 kf1 = *(const bf16x8*)(ksb + (32 + l32) * 256 + ch);
            sc0 = __builtin_amdgcn_mfma_f32_32x32x16_bf16(kf0, qf[d8], sc0, 0, 0, 0);
            sc1 = __builtin_amdgcn_mfma_f32_32x32x16_bf16(kf1, qf[d8], sc1, 0, 0, 0);
        }

        float tmax = -INFINITY;
        int last = (kb == nkb - 1);
        #pragma unroll
        for (int r = 0; r < 16; r++) {
            int kl = (r & 3) + 8 * (r >> 2) + 4 * h2;
            float s0 = sc0[r] * inv + slope * (float)(k0 + kl);
            float s1 = sc1[r] * inv + slope * (float)(k0 + 32 + kl);
            if (last) {
                if (k0 + kl > qg) s0 = -INFINITY;
                if (k0 + 32 + kl > qg) s1 = -INFINITY;
            }
            sc0[r] = s0; sc1[r] = s1;
            tmax = fmaxf(tmax, fmaxf(s0, s1));
        }
        tmax = fmaxf(tmax, __shfl_xor(tmax, 32));
        if (!__all(tmax <= m + 8.f)) {          // defer-max (T13)
            float mnew = fmaxf(m, tmax);
            float sca = __expf(m - mnew);
            m = mnew;
            lsum *= sca;
            #pragma unroll
            for (int db = 0; db < 4; db++)
                #pragma unroll
                for (int e = 0; e < 16; e++) ao[db][e] *= sca;
        }
        float psum = 0.f;
        #pragma unroll
        for (int r = 0; r < 16; r++) {
            sc0[r] = __expf(sc0[r] - m); psum += sc0[r];
            sc1[r] = __expf(sc1[r] - m); psum += sc1[r];
        }
        psum += __shfl_xor(psum, 32);
        lsum += psum;

        #pragma unroll
        for (int kstep = 0; kstep < 4; kstep++) {
            const int ks1 = kstep & 1;
            float a0, a1, a2, a3, b0, b1, b2, b3;
            if (kstep < 2) {
                a0 = sc0[8*ks1+0]; a1 = sc0[8*ks1+1]; a2 = sc0[8*ks1+2]; a3 = sc0[8*ks1+3];
                b0 = sc0[8*ks1+4]; b1 = sc0[8*ks1+5]; b2 = sc0[8*ks1+6]; b3 = sc0[8*ks1+7];
            } else {
                a0 = sc1[8*ks1+0]; a1 = sc1[8*ks1+1]; a2 = sc1[8*ks1+2]; a3 = sc1[8*ks1+3];
                b0 = sc1[8*ks1+4]; b1 = sc1[8*ks1+5]; b2 = sc1[8*ks1+6]; b3 = sc1[8*ks1+7];
            }
            unsigned ku0 = pack_bf2(h2 ? b0 : a0, h2 ? b1 : a1);
            unsigned ku1 = pack_bf2(h2 ? b2 : a2, h2 ? b3 : a3);
            unsigned su0 = pack_bf2(h2 ? a0 : b0, h2 ? a1 : b1);
            unsigned su1 = pack_bf2(h2 ? a2 : b2, h2 ? a3 : b3);
            unsigned r0 = (unsigned)__shfl_xor((int)su0, 32);
            unsigned r1 = (unsigned)__shfl_xor((int)su1, 32);
            union { int4 i; bf16x8 v; } u;
            u.i.x = h2 ? (int)r0  : (int)ku0;
            u.i.y = h2 ? (int)r1  : (int)ku1;
            u.i.z = h2 ? (int)ku0 : (int)r0;
            u.i.w = h2 ? (int)ku1 : (int)r1;
            bf16x8 pf = u.v;
            int ch = ((kstep * 2 + h2) ^ (l32 & 7)) << 4;
            #pragma unroll
            for (int db = 0; db < 4; db++) {
                bf16x8 vf = *(const bf16x8*)(vsb + (db * 32 + l32) * 128 + ch);
                ao[db] = __builtin_amdgcn_mfma_f32_32x32x16_bf16(vf, pf, ao[db], 0, 0, 0);
            }
        }
    }

    float rl = 1.f / lsum;
    #pragma unroll
    for (int db = 0; db < 4; db++)
        #pragma unroll
        for (int g = 0; g < 4; g++) {
            ushort4 o;
            o.x = f2bf(ao[db][g*4+0] * rl);
            o.y = f2bf(ao[db][g*4+1] * rl);
            o.z = f2bf(ao[db][g*4+2] * rl);
            o.w = f2bf(ao[db][g*4+3] * rl);
            *(ushort4*)(ctx + (size_t)qg * HH + n * HD + db * 32 + g * 8 + h2 * 4) = o;
        }
}

extern "C" void kernel_launch(void* const* d_in, const int* in_sizes, int n_in,
                              void* d_out, int out_size, void* d_ws, size_t ws_size,
                              hipStream_t stream) {
    const float* hs    = (const float*)d_in[0];
    const float* ln1g  = (const float*)d_in[4];
    const float* ln1b  = (const float*)d_in[5];
    const float* qkvw  = (const float*)d_in[6];
    const float* qkvb  = (const float*)d_in[7];
    const float* dw    = (const float*)d_in[8];
    const float* db    = (const float*)d_in[9];
    const float* ln2g  = (const float*)d_in[10];
    const float* ln2b  = (const float*)d_in[11];
    const float* f1w   = (const float*)d_in[12];
    const float* f1b   = (const float*)d_in[13];
    const float* f2w   = (const float*)d_in[14];
    const float* f2b   = (const float*)d_in[15];
    float* out = (float*)d_out;

    char* ws = (char*)d_ws;
    size_t off = 0;
    auto alloc = [&](size_t nbytes) {
        void* p = ws + off; off += (nbytes + 255) & ~(size_t)255; return p;
    };
    unsigned short* xbf  = (unsigned short*)alloc((size_t)SQ * HH * 2);        // [0, 8.39M)
    unsigned short* qkvB = (unsigned short*)alloc((size_t)SQ * QKVW * 2);      // [8.39M, 33.55M)
    unsigned short* vtB  = (unsigned short*)alloc((size_t)NHEAD * HD * SQ * 2);// [33.55M, 41.94M)
    unsigned short* ctx  = (unsigned short*)alloc((size_t)SQ * HH * 2);        // [41.94M, 50.33M)
    float*          attn = (float*)alloc((size_t)SQ * HH * 4);                 // [50.33M, 67.11M)
    unsigned short* y    = (unsigned short*)alloc((size_t)SQ * HH * 2);        // [67.11M, 75.50M)
    unsigned short* hdn  = (unsigned short*)alloc((size_t)SQ * 4 * HH * 2);    // [75.50M, 109.05M)
    unsigned short* wbuf = (unsigned short*)alloc((size_t)4 * HH * HH * 2);    // [109.05M, 142.61M)

    const size_t PQ = (size_t)SQ * HH;      // floats per partial (16.78 MB)
    float* part = (float*)ws;               // partials overlap dead early buffers

    ln_kernel<<<SQ, 256, 0, stream>>>(hs, ln1g, ln1b, xbf);

    // QKV: M=2048,N=6144,K=2048. grid 48x16 = 768 blocks (3/CU); CH=8,CW=12.
    cvt_kernel<<<2048, 256, 0, stream>>>(qkvw, wbuf, QKVW * HH / 4);
    gemm128<2, 0><<<dim3(QKVW / 128, SQ / 128, 1), 256, 0, stream>>>(
        xbf, wbuf, qkvb, qkvB, vtB, nullptr, QKVW, HH, HH, HH, HH, 8, 12);

    attn_kernel<<<512, 128, 0, stream>>>(qkvB, vtB, ctx);

    // dense: split-K x4 (16x16x4 = 1024 blocks, kLen=512); CH=16,CW=8.
    // partials: p0,p1 at ws[0,33.55M) (dead xbf+qkvB); p2,p3 in dead hdn.
    cvt_kernel<<<1024, 256, 0, stream>>>(dw, wbuf, HH * HH / 4);
    gemm128<0, 0><<<dim3(HH / 128, SQ / 128, 4), 256, 0, stream>>>(
        ctx, wbuf, nullptr, part, (unsigned short*)((float*)hdn + PQ), hdn,
        HH, HH, HH, HH / 4, HH, 16, 8);
    reduceN_kernel<4><<<2048, 256, 0, stream>>>(
        part, part + PQ, (float*)hdn, (float*)hdn + PQ, hs, db, attn, SQ * HH / 4, HH / 4 - 1);

    ln_kernel<<<SQ, 256, 0, stream>>>(attn, ln2g, ln2b, y);

    // FC1: M=2048,N=8192,K=2048. grid 64x16 = 1024 blocks (4/CU); CH=8,CW=16.
    cvt_kernel<<<2048, 256, 0, stream>>>(f1w, wbuf, 4 * HH * HH / 4);
    gemm128<1, 1><<<dim3(4 * HH / 128, SQ / 128, 1), 256, 0, stream>>>(
        y, wbuf, f1b, hdn, nullptr, nullptr, 4 * HH, HH, HH, HH, HH, 8, 16);

    // FC2: split-K x3 (16x16x3 = 768 blocks; kLen=2752 -> 2752/2752/2688,
    // Ktot=8192 clamps bz=2). CH=12,CW=8 (8 XCDs x 96 = 768, bijective).
    // Partials p0,p1,p2 at ws[0, 50.33M) = dead xbf+qkvB+vtB+ctx, ending
    // exactly at live attn (50,331,648 B). wbuf holds f2w bf16 (33.55 MB, full).
    cvt_kernel<<<2048, 256, 0, stream>>>(f2w, wbuf, 4 * HH * HH / 4);
    gemm128<0, 0><<<dim3(HH / 128, SQ / 128, 3), 256, 0, stream>>>(
        hdn, wbuf, nullptr, part, nullptr, part + 2 * PQ,
        HH, 4 * HH, 4 * HH, 2752, 4 * HH, 12, 8);
    reduceN_kernel<3><<<2048, 256, 0, stream>>>(
        part, part + PQ, part + 2 * PQ, nullptr, attn, f2b, out, SQ * HH / 4, HH / 4 - 1);
}